// Round 1
// baseline (455.127 us; speedup 1.0000x reference)
//
#include <hip/hip_runtime.h>

// ---------------------------------------------------------------------------
// Transformer block on MI355X (gfx950), bf16 MFMA pipeline, fp32 residual/LN.
//   x:[2,2048,1024]  LN over T (ddof=1)  -> QKV GEMM -> causal flash attn
//   -> +residual -> LN over T -> MLP(4096, ReLU) -> +residual
// ---------------------------------------------------------------------------

typedef __bf16 bf16x8 __attribute__((ext_vector_type(8)));
typedef float f32x4 __attribute__((ext_vector_type(4)));
typedef unsigned short u16;
typedef u16 u16x8 __attribute__((ext_vector_type(8)));
typedef u16 u16x4 __attribute__((ext_vector_type(4)));

__device__ __forceinline__ u16 f2bf(float f) {  // RNE f32->bf16
  unsigned u = __builtin_bit_cast(unsigned, f);
  u += 0x7fffu + ((u >> 16) & 1u);
  return (u16)(u >> 16);
}
__device__ __forceinline__ bf16x8 ldbf8(const u16* p) {
  return __builtin_bit_cast(bf16x8, *reinterpret_cast<const u16x8*>(p));
}

// ---------------- weight transpose (f32 [K][N] -> bf16 [N][K]) -------------
__global__ __launch_bounds__(256) void transpose_big(const float* __restrict__ in,
                                                     u16* __restrict__ out, int K, int N) {
  __shared__ float tile[64][65];
  const int k0 = blockIdx.x * 64, n0 = blockIdx.y * 64;
  const int c = threadIdx.x & 63, rg = threadIdx.x >> 6;
#pragma unroll
  for (int i = 0; i < 16; ++i) {
    int r = rg * 16 + i;
    tile[r][c] = in[(size_t)(k0 + r) * N + n0 + c];
  }
  __syncthreads();
#pragma unroll
  for (int i = 0; i < 16; ++i) {
    int nl = rg * 16 + i;
    out[(size_t)(n0 + nl) * K + k0 + c] = f2bf(tile[c][nl]);
  }
}

// Wq/Wk/Wv: [H][1024][64] f32 -> rows (zoff + h*64 + d) of [3072][1024] bf16
__global__ __launch_bounds__(256) void transpose_head(const float* __restrict__ W,
                                                      u16* __restrict__ out, int zoff) {
  __shared__ float tile[64][65];
  const int k0 = blockIdx.x * 64, h = blockIdx.y;
  const float* in = W + (size_t)h * 1024 * 64;
  const int c = threadIdx.x & 63, rg = threadIdx.x >> 6;
#pragma unroll
  for (int i = 0; i < 16; ++i) {
    int r = rg * 16 + i;
    tile[r][c] = in[(size_t)(k0 + r) * 64 + c];
  }
  __syncthreads();
#pragma unroll
  for (int i = 0; i < 16; ++i) {
    int nl = rg * 16 + i;
    out[(size_t)(zoff + h * 64 + nl) * 1024 + k0 + c] = f2bf(tile[c][nl]);
  }
}

// ---------------- LayerNorm over sequence axis T (per (b,c)) ---------------
// partial sums over 256-row chunks: part[bc][chunk] = (sum, sumsq)
__global__ __launch_bounds__(256) void ln_partial(const float* __restrict__ x,
                                                  float2* __restrict__ part) {
  const int b = blockIdx.x >> 4, c0 = (blockIdx.x & 15) * 64;
  const int c = c0 + (threadIdx.x & 63), tg = threadIdx.x >> 6;
  const int t0 = blockIdx.y * 256 + tg * 64;
  float s = 0.f, sq = 0.f;
  const float* p = x + (size_t)(b * 2048 + t0) * 1024 + c;
#pragma unroll 8
  for (int i = 0; i < 64; ++i) {
    float v = p[(size_t)i * 1024];
    s += v; sq += v * v;
  }
  __shared__ float ss[256], sb[256];
  ss[threadIdx.x] = s; sb[threadIdx.x] = sq;
  __syncthreads();
  if (threadIdx.x < 64) {
    s  = ss[threadIdx.x] + ss[threadIdx.x + 64] + ss[threadIdx.x + 128] + ss[threadIdx.x + 192];
    sq = sb[threadIdx.x] + sb[threadIdx.x + 64] + sb[threadIdx.x + 128] + sb[threadIdx.x + 192];
    part[(size_t)(b * 1024 + c) * 8 + blockIdx.y] = make_float2(s, sq);
  }
}

__global__ __launch_bounds__(256) void ln_stats(const float2* __restrict__ part,
                                                float2* __restrict__ stats) {
  const int bc = blockIdx.x * 256 + threadIdx.x;  // 2048 total
  float s = 0.f, sq = 0.f;
#pragma unroll
  for (int i = 0; i < 8; ++i) {
    float2 v = part[(size_t)bc * 8 + i];
    s += v.x; sq += v.y;
  }
  const float mean = s * (1.0f / 2048.0f);
  const float var = (sq - 2048.0f * mean * mean) * (1.0f / 2047.0f);  // ddof=1
  stats[bc] = make_float2(mean, rsqrtf(var + 1e-5f));
}

__global__ __launch_bounds__(256) void ln_apply(const float* __restrict__ x,
                                                const float2* __restrict__ stats,
                                                const float* __restrict__ g,
                                                const float* __restrict__ be,
                                                u16* __restrict__ out) {
  const size_t flat = ((size_t)blockIdx.x * 256 + threadIdx.x) * 4;
  const int b = (int)(flat >> 21);     // T*C = 2^21
  const int c = (int)(flat & 1023);
  float4 xv = *reinterpret_cast<const float4*>(x + flat);
  float vs[4] = {xv.x, xv.y, xv.z, xv.w};
  u16x4 o;
#pragma unroll
  for (int j = 0; j < 4; ++j) {
    float2 st = stats[b * 1024 + c + j];
    o[j] = f2bf(g[c + j] * (vs[j] - st.x) * st.y + be[c + j]);
  }
  *reinterpret_cast<u16x4*>(out + flat) = o;
}

// ---------------- GEMM: C[M,N] = A[M,K](bf16) x Bt[N,K](bf16)^T ------------
// EPI 0: store bf16.  1: +bias, ReLU, bf16.  2: +bias +resid, f32.
template <int MI, int NI, int EPI>
__global__ __launch_bounds__(256) void gemm_kernel(const u16* __restrict__ A,
                                                   const u16* __restrict__ Bt,
                                                   u16* __restrict__ outb,
                                                   float* __restrict__ outf,
                                                   const float* __restrict__ bias,
                                                   const float* __restrict__ resid,
                                                   int N, int K) {
  constexpr int BM = MI * 32, BN = NI * 32;   // 2x2 waves per block
  constexpr int SA = 40;                       // 32 + 8 pad (80B rows: 16B-aligned, 2-way banks)
  __shared__ alignas(16) u16 sA[BM * SA];
  __shared__ alignas(16) u16 sB[BN * SA];
  const int n0 = blockIdx.x * BN, m0 = blockIdx.y * BM;
  const int tid = threadIdx.x;
  const int lane = tid & 63, wid = tid >> 6;
  const int wm = (wid >> 1) * (MI * 16), wn = (wid & 1) * (NI * 16);
  const int lr = lane & 15, lg = lane >> 4;
  constexpr int ACH = (BM * 4) / 256;
  constexpr int BCH = (BN * 4) / 256;
  static_assert(ACH >= 1 && BCH >= 1, "tile too small");
  f32x4 acc[MI][NI] = {};

  for (int k0 = 0; k0 < K; k0 += 32) {
    __syncthreads();  // previous iteration's frag reads done before overwrite
#pragma unroll
    for (int j = 0; j < ACH; ++j) {
      int ch = tid + j * 256, row = ch >> 2, ko = (ch & 3) * 8;
      *reinterpret_cast<u16x8*>(&sA[row * SA + ko]) =
          *reinterpret_cast<const u16x8*>(A + (size_t)(m0 + row) * K + k0 + ko);
    }
#pragma unroll
    for (int j = 0; j < BCH; ++j) {
      int ch = tid + j * 256, row = ch >> 2, ko = (ch & 3) * 8;
      *reinterpret_cast<u16x8*>(&sB[row * SA + ko]) =
          *reinterpret_cast<const u16x8*>(Bt + (size_t)(n0 + row) * K + k0 + ko);
    }
    __syncthreads();
    bf16x8 af[MI], bfr[NI];
#pragma unroll
    for (int mi = 0; mi < MI; ++mi) af[mi] = ldbf8(&sA[(wm + mi * 16 + lr) * SA + lg * 8]);
#pragma unroll
    for (int ni = 0; ni < NI; ++ni) bfr[ni] = ldbf8(&sB[(wn + ni * 16 + lr) * SA + lg * 8]);
#pragma unroll
    for (int mi = 0; mi < MI; ++mi)
#pragma unroll
      for (int ni = 0; ni < NI; ++ni)
        acc[mi][ni] = __builtin_amdgcn_mfma_f32_16x16x32_bf16(af[mi], bfr[ni], acc[mi][ni], 0, 0, 0);
  }

#pragma unroll
  for (int mi = 0; mi < MI; ++mi)
#pragma unroll
    for (int ni = 0; ni < NI; ++ni)
#pragma unroll
      for (int r = 0; r < 4; ++r) {
        const int row = m0 + wm + mi * 16 + lg * 4 + r;   // verified C/D mapping (m89/m91)
        const int col = n0 + wn + ni * 16 + lr;
        float v = acc[mi][ni][r];
        if (EPI == 0) {
          outb[(size_t)row * N + col] = f2bf(v);
        } else if (EPI == 1) {
          v += bias[col];
          v = fmaxf(v, 0.f);
          outb[(size_t)row * N + col] = f2bf(v);
        } else {
          v += bias[col] + resid[(size_t)row * N + col];
          outf[(size_t)row * N + col] = v;
        }
      }
}

// ---------------- causal flash attention -----------------------------------
// qkv: bf16 [B*T][3072] (q|k|v each [T][H*64] per b). x2 = x + attn_out (f32).
__global__ __launch_bounds__(256) void attn_kernel(const u16* __restrict__ qkv,
                                                   const float* __restrict__ x,
                                                   float* __restrict__ x2) {
  const int qb = blockIdx.x, bh = blockIdx.y;
  const int b = bh >> 4, h = bh & 15;
  const int q0 = qb * 64;
  const int tid = threadIdx.x, lane = tid & 63, w = tid >> 6;
  const int lr = lane & 15, lg = lane >> 4;
  __shared__ alignas(16) u16 sV[64 * 40];       // V^T tile: [d=64][s=32] stride 40
  __shared__ alignas(16) u16 sP[4][16 * 40];    // per-wave P tile [16q][32s] stride 40
  const size_t base = (size_t)b * 2048 * 3072;

  const int qrow = q0 + w * 16 + lr;
  const u16* qp = qkv + base + (size_t)qrow * 3072 + h * 64 + lg * 8;
  const bf16x8 aq0 = ldbf8(qp), aq1 = ldbf8(qp + 32);

  float m_i[4], l_i[4];
  f32x4 acc[4];
#pragma unroll
  for (int r = 0; r < 4; ++r) { m_i[r] = -1e30f; l_i[r] = 0.f; }
#pragma unroll
  for (int dn = 0; dn < 4; ++dn) acc[dn] = f32x4{0.f, 0.f, 0.f, 0.f};

  const int ntiles = (q0 + 64) >> 5;
  for (int st = 0; st < ntiles; ++st) {
    const int s0 = st * 32;
    __syncthreads();
    {  // stage V^T
      const int s = tid >> 3, d0 = (tid & 7) * 8;
      u16x8 v = *reinterpret_cast<const u16x8*>(
          qkv + base + (size_t)(s0 + s) * 3072 + 2048 + h * 64 + d0);
#pragma unroll
      for (int j = 0; j < 8; ++j) sV[(d0 + j) * 40 + s] = v[j];
    }
    __syncthreads();

    f32x4 sf[2];
#pragma unroll
    for (int sn = 0; sn < 2; ++sn) {  // S[16q x 16s] = Q . K^T
      const u16* kp = qkv + base + (size_t)(s0 + sn * 16 + lr) * 3072 + 1024 + h * 64 + lg * 8;
      f32x4 z = {0.f, 0.f, 0.f, 0.f};
      z = __builtin_amdgcn_mfma_f32_16x16x32_bf16(aq0, ldbf8(kp), z, 0, 0, 0);
      z = __builtin_amdgcn_mfma_f32_16x16x32_bf16(aq1, ldbf8(kp + 32), z, 0, 0, 0);
      sf[sn] = z;
    }

#pragma unroll
    for (int r = 0; r < 4; ++r) {  // online softmax, row = lg*4+r
      const int q = q0 + w * 16 + lg * 4 + r;
      float v0 = sf[0][r] * 0.03125f;   // scale = C^-0.5 = 1/32
      float v1 = sf[1][r] * 0.03125f;
      if (s0 + lr > q) v0 = -1e30f;
      if (s0 + 16 + lr > q) v1 = -1e30f;
      float mx = fmaxf(v0, v1);
      mx = fmaxf(mx, __shfl_xor(mx, 1, 16));
      mx = fmaxf(mx, __shfl_xor(mx, 2, 16));
      mx = fmaxf(mx, __shfl_xor(mx, 4, 16));
      mx = fmaxf(mx, __shfl_xor(mx, 8, 16));
      const float mnew = fmaxf(m_i[r], mx);
      const float alpha = __expf(m_i[r] - mnew);
      const float p0 = __expf(v0 - mnew), p1 = __expf(v1 - mnew);
      float rs = p0 + p1;
      rs += __shfl_xor(rs, 1, 16);
      rs += __shfl_xor(rs, 2, 16);
      rs += __shfl_xor(rs, 4, 16);
      rs += __shfl_xor(rs, 8, 16);
      l_i[r] = l_i[r] * alpha + rs;
      m_i[r] = mnew;
#pragma unroll
      for (int dn = 0; dn < 4; ++dn) acc[dn][r] *= alpha;
      const int prow = lg * 4 + r;
      sP[w][prow * 40 + lr] = f2bf(p0);
      sP[w][prow * 40 + 16 + lr] = f2bf(p1);
    }
    __syncthreads();  // order P writes (cross-lane) before A-frag reads

    const bf16x8 pa = ldbf8(&sP[w][lr * 40 + lg * 8]);
#pragma unroll
    for (int dn = 0; dn < 4; ++dn) {  // O += P . V
      bf16x8 vf = ldbf8(&sV[(dn * 16 + lr) * 40 + lg * 8]);
      acc[dn] = __builtin_amdgcn_mfma_f32_16x16x32_bf16(pa, vf, acc[dn], 0, 0, 0);
    }
  }

  const int trow = q0 + w * 16 + lg * 4;
#pragma unroll
  for (int r = 0; r < 4; ++r) {
    const float inv = 1.0f / l_i[r];
#pragma unroll
    for (int dn = 0; dn < 4; ++dn) {
      const size_t idx = ((size_t)(b * 2048 + trow + r)) * 1024 + h * 64 + dn * 16 + lr;
      x2[idx] = x[idx] + acc[dn][r] * inv;
    }
  }
}

// ---------------------------------------------------------------------------
extern "C" void kernel_launch(void* const* d_in, const int* in_sizes, int n_in,
                              void* d_out, int out_size, void* d_ws, size_t ws_size,
                              hipStream_t stream) {
  const float* x   = (const float*)d_in[0];
  const float* Wq  = (const float*)d_in[1];
  const float* Wk  = (const float*)d_in[2];
  const float* Wv  = (const float*)d_in[3];
  const float* W1  = (const float*)d_in[4];
  const float* b1  = (const float*)d_in[5];
  const float* W2  = (const float*)d_in[6];
  const float* b2  = (const float*)d_in[7];
  const float* g1  = (const float*)d_in[8];
  const float* be1 = (const float*)d_in[9];
  const float* g2  = (const float*)d_in[10];
  const float* be2 = (const float*)d_in[11];
  float* out = (float*)d_out;

  char* ws = (char*)d_ws;
  size_t off = 0;
  auto alloc = [&](size_t bytes) { char* p = ws + off; off += (bytes + 255) & ~(size_t)255; return p; };
  u16*    hbuf  = (u16*)alloc(4096ull * 1024 * 2);          // ln1 out, then ln2 out
  u16*    bigb  = (u16*)alloc(4096ull * 4096 * 2);          // qkv [4096][3072], later h1 [4096][4096]
  float*  x2    = (float*)alloc(4096ull * 1024 * 4);        // x + attn
  u16*    wqkvt = (u16*)alloc(3072ull * 1024 * 2);
  u16*    w1t   = (u16*)alloc(4096ull * 1024 * 2);
  u16*    w2t   = (u16*)alloc(1024ull * 4096 * 2);
  float2* part  = (float2*)alloc(2048ull * 8 * 8);
  float2* stats = (float2*)alloc(2048ull * 8);
  (void)ws_size; (void)in_sizes; (void)n_in; (void)out_size;

  // weight prep (bf16, B-transposed)
  transpose_head<<<dim3(16, 16), 256, 0, stream>>>(Wq, wqkvt, 0);
  transpose_head<<<dim3(16, 16), 256, 0, stream>>>(Wk, wqkvt, 1024);
  transpose_head<<<dim3(16, 16), 256, 0, stream>>>(Wv, wqkvt, 2048);
  transpose_big<<<dim3(16, 64), 256, 0, stream>>>(W1, w1t, 1024, 4096);
  transpose_big<<<dim3(64, 16), 256, 0, stream>>>(W2, w2t, 4096, 1024);

  // LN1 (over T) -> hbuf (bf16)
  ln_partial<<<dim3(32, 8), 256, 0, stream>>>(x, part);
  ln_stats<<<8, 256, 0, stream>>>(part, stats);
  ln_apply<<<4096, 256, 0, stream>>>(x, stats, g1, be1, hbuf);

  // QKV GEMM: [4096,1024] x [1024,3072] -> bigb (bf16)
  gemm_kernel<4, 4, 0><<<dim3(24, 32), 256, 0, stream>>>(hbuf, wqkvt, bigb, nullptr, nullptr, nullptr, 3072, 1024);

  // attention + residual -> x2 (f32)
  attn_kernel<<<dim3(32, 32), 256, 0, stream>>>(bigb, x, x2);

  // LN2 (over T) -> hbuf (bf16)
  ln_partial<<<dim3(32, 8), 256, 0, stream>>>(x2, part);
  ln_stats<<<8, 256, 0, stream>>>(part, stats);
  ln_apply<<<4096, 256, 0, stream>>>(x2, stats, g2, be2, hbuf);

  // MLP1: relu(h @ W1 + b1) -> bigb (bf16 [4096][4096])
  gemm_kernel<4, 4, 1><<<dim3(32, 32), 256, 0, stream>>>(hbuf, w1t, bigb, nullptr, b1, nullptr, 4096, 1024);

  // MLP2: x2 + h1 @ W2 + b2 -> out (f32)
  gemm_kernel<4, 2, 2><<<dim3(16, 32), 256, 0, stream>>>(bigb, w2t, nullptr, out, b2, x2, 1024, 4096);
}

// Round 2
// 370.512 us; speedup vs baseline: 1.2284x; 1.2284x over previous
//
#include <hip/hip_runtime.h>

// ---------------------------------------------------------------------------
// Transformer block on MI355X (gfx950), bf16 MFMA pipeline, fp32 residual/LN.
//   x:[2,2048,1024]  LN over T (ddof=1) -> QK GEMM + V^T GEMM -> causal flash
//   attn (dbuf LDS, swizzled global_load_lds) -> +resid -> LN -> MLP -> +resid
// ---------------------------------------------------------------------------

typedef __bf16 bf16x8 __attribute__((ext_vector_type(8)));
typedef float f32x4 __attribute__((ext_vector_type(4)));
typedef unsigned short u16;
typedef u16 u16x8 __attribute__((ext_vector_type(8)));
typedef u16 u16x4 __attribute__((ext_vector_type(4)));

#define MFMA16 __builtin_amdgcn_mfma_f32_16x16x32_bf16

__device__ __forceinline__ u16 f2bf(float f) {  // native v_cvt (RNE)
  return __builtin_bit_cast(u16, (__bf16)f);
}
__device__ __forceinline__ bf16x8 ldbf8(const u16* p) {
  return __builtin_bit_cast(bf16x8, *reinterpret_cast<const u16x8*>(p));
}
// async global->LDS, 16B per lane, dest = wave-uniform base + lane*16
__device__ __forceinline__ void gll16(const void* g, void* l) {
  __builtin_amdgcn_global_load_lds((const __attribute__((address_space(1))) void*)g,
                                   (__attribute__((address_space(3))) void*)l, 16, 0, 0);
}

// ---------------- weight transpose (f32 [K][N] -> bf16 [N][K]) -------------
__global__ __launch_bounds__(256) void transpose_big(const float* __restrict__ in,
                                                     u16* __restrict__ out, int K, int N) {
  __shared__ float tile[64][65];
  const int k0 = blockIdx.x * 64, n0 = blockIdx.y * 64;
  const int c = threadIdx.x & 63, rg = threadIdx.x >> 6;
#pragma unroll
  for (int i = 0; i < 16; ++i) {
    int r = rg * 16 + i;
    tile[r][c] = in[(size_t)(k0 + r) * N + n0 + c];
  }
  __syncthreads();
#pragma unroll
  for (int i = 0; i < 16; ++i) {
    int nl = rg * 16 + i;
    out[(size_t)(n0 + nl) * K + k0 + c] = f2bf(tile[c][nl]);
  }
}

// Wq/Wk/Wv: [H][1024][64] f32 -> rows (zoff + h*64 + d) of [3072][1024] bf16
__global__ __launch_bounds__(256) void transpose_head(const float* __restrict__ W,
                                                      u16* __restrict__ out, int zoff) {
  __shared__ float tile[64][65];
  const int k0 = blockIdx.x * 64, h = blockIdx.y;
  const float* in = W + (size_t)h * 1024 * 64;
  const int c = threadIdx.x & 63, rg = threadIdx.x >> 6;
#pragma unroll
  for (int i = 0; i < 16; ++i) {
    int r = rg * 16 + i;
    tile[r][c] = in[(size_t)(k0 + r) * 64 + c];
  }
  __syncthreads();
#pragma unroll
  for (int i = 0; i < 16; ++i) {
    int nl = rg * 16 + i;
    out[(size_t)(zoff + h * 64 + nl) * 1024 + k0 + c] = f2bf(tile[c][nl]);
  }
}

// ---------------- LayerNorm over sequence axis T (per (b,c)) ---------------
__global__ __launch_bounds__(256) void ln_partial(const float* __restrict__ x,
                                                  float2* __restrict__ part) {
  const int b = blockIdx.x >> 4, c0 = (blockIdx.x & 15) * 64;
  const int c = c0 + (threadIdx.x & 63), tg = threadIdx.x >> 6;
  const int t0 = blockIdx.y * 256 + tg * 64;
  float s = 0.f, sq = 0.f;
  const float* p = x + (size_t)(b * 2048 + t0) * 1024 + c;
#pragma unroll 8
  for (int i = 0; i < 64; ++i) {
    float v = p[(size_t)i * 1024];
    s += v; sq += v * v;
  }
  __shared__ float ss[256], sb[256];
  ss[threadIdx.x] = s; sb[threadIdx.x] = sq;
  __syncthreads();
  if (threadIdx.x < 64) {
    s  = ss[threadIdx.x] + ss[threadIdx.x + 64] + ss[threadIdx.x + 128] + ss[threadIdx.x + 192];
    sq = sb[threadIdx.x] + sb[threadIdx.x + 64] + sb[threadIdx.x + 128] + sb[threadIdx.x + 192];
    part[(size_t)(b * 1024 + c) * 8 + blockIdx.y] = make_float2(s, sq);
  }
}

__global__ __launch_bounds__(256) void ln_stats(const float2* __restrict__ part,
                                                float2* __restrict__ stats) {
  const int bc = blockIdx.x * 256 + threadIdx.x;
  float s = 0.f, sq = 0.f;
#pragma unroll
  for (int i = 0; i < 8; ++i) {
    float2 v = part[(size_t)bc * 8 + i];
    s += v.x; sq += v.y;
  }
  const float mean = s * (1.0f / 2048.0f);
  const float var = (sq - 2048.0f * mean * mean) * (1.0f / 2047.0f);  // ddof=1
  stats[bc] = make_float2(mean, rsqrtf(var + 1e-5f));
}

__global__ __launch_bounds__(256) void ln_apply(const float* __restrict__ x,
                                                const float2* __restrict__ stats,
                                                const float* __restrict__ g,
                                                const float* __restrict__ be,
                                                u16* __restrict__ out) {
  const size_t flat = ((size_t)blockIdx.x * 256 + threadIdx.x) * 4;
  const int b = (int)(flat >> 21);
  const int c = (int)(flat & 1023);
  float4 xv = *reinterpret_cast<const float4*>(x + flat);
  float vs[4] = {xv.x, xv.y, xv.z, xv.w};
  u16x4 o;
#pragma unroll
  for (int j = 0; j < 4; ++j) {
    float2 st = stats[b * 1024 + c + j];
    o[j] = f2bf(g[c + j] * (vs[j] - st.x) * st.y + be[c + j]);
  }
  *reinterpret_cast<u16x4*>(out + flat) = o;
}

// ---------------- GEMM (m97 structure): C = A[M,K] x Bt[N,K]^T -------------
// global_load_lds width-16 into linear [rows][32] LDS (conflict-free frags).
// EPI 0: store bf16.  1: +bias, ReLU, bf16.  2: +bias +resid, f32.
template <int MI, int NI, int EPI>
__global__ __launch_bounds__(256) void gemm_kernel(const u16* __restrict__ A,
                                                   const u16* __restrict__ Bt,
                                                   u16* __restrict__ outb,
                                                   float* __restrict__ outf,
                                                   const float* __restrict__ bias,
                                                   const float* __restrict__ resid,
                                                   int N, int K) {
  constexpr int BM = MI * 32, BN = NI * 32;   // 2x2 waves per block
  __shared__ alignas(16) u16 sA[BM * 32];
  __shared__ alignas(16) u16 sB[BN * 32];
  const int n0 = blockIdx.x * BN, m0 = blockIdx.y * BM;
  const int tid = threadIdx.x, lane = tid & 63, wid = tid >> 6;
  const int wm = (wid >> 1) * (MI * 16), wn = (wid & 1) * (NI * 16);
  const int lr = lane & 15, lg = lane >> 4;
  constexpr int CA = BM / 64;   // 1KB chunks per wave for A
  constexpr int CB = BN / 64;
  f32x4 acc[MI][NI] = {};

  for (int k0 = 0; k0 < K; k0 += 32) {
    __syncthreads();  // WAR: prior iteration's frag reads complete
#pragma unroll
    for (int i = 0; i < CA; ++i) {
      const int c = wid * CA + i, g = c * 64 + lane;
      gll16(A + (size_t)(m0 + (g >> 2)) * K + k0 + (g & 3) * 8, &sA[c * 512]);
    }
#pragma unroll
    for (int i = 0; i < CB; ++i) {
      const int c = wid * CB + i, g = c * 64 + lane;
      gll16(Bt + (size_t)(n0 + (g >> 2)) * K + k0 + (g & 3) * 8, &sB[c * 512]);
    }
    __syncthreads();  // drains vmcnt -> tile visible to all waves
    bf16x8 af[MI], bfr[NI];
#pragma unroll
    for (int mi = 0; mi < MI; ++mi) af[mi] = ldbf8(&sA[(wm + mi * 16 + lr) * 32 + lg * 8]);
#pragma unroll
    for (int ni = 0; ni < NI; ++ni) bfr[ni] = ldbf8(&sB[(wn + ni * 16 + lr) * 32 + lg * 8]);
#pragma unroll
    for (int mi = 0; mi < MI; ++mi)
#pragma unroll
      for (int ni = 0; ni < NI; ++ni)
        acc[mi][ni] = MFMA16(af[mi], bfr[ni], acc[mi][ni], 0, 0, 0);
  }

#pragma unroll
  for (int mi = 0; mi < MI; ++mi)
#pragma unroll
    for (int ni = 0; ni < NI; ++ni)
#pragma unroll
      for (int r = 0; r < 4; ++r) {
        const int row = m0 + wm + mi * 16 + lg * 4 + r;   // C/D: row=(lane>>4)*4+reg
        const int col = n0 + wn + ni * 16 + lr;           //      col=lane&15
        float v = acc[mi][ni][r];
        if (EPI == 0) {
          outb[(size_t)row * N + col] = f2bf(v);
        } else if (EPI == 1) {
          v += bias[col];
          v = fmaxf(v, 0.f);
          outb[(size_t)row * N + col] = f2bf(v);
        } else {
          v += bias[col] + resid[(size_t)row * N + col];
          outf[(size_t)row * N + col] = v;
        }
      }
}

// ---------------- causal flash attention -----------------------------------
// qk: bf16 [4096 tok][2048] (Q|K per head).  vt: bf16 [1024 hd][4096 tok].
// KVBLK=64, double-buffered K/V via swizzled-source global_load_lds.
__global__ __launch_bounds__(256) void attn_kernel(const u16* __restrict__ qk,
                                                   const u16* __restrict__ vt,
                                                   const float* __restrict__ x,
                                                   float* __restrict__ x2) {
  const int qb = (int)gridDim.x - 1 - (int)blockIdx.x;  // heavy blocks first
  const int bh = blockIdx.y, b = bh >> 4, h = bh & 15;
  const int q0 = qb * 64;
  const int tid = threadIdx.x, lane = tid & 63, w = tid >> 6;
  const int lr = lane & 15, lg = lane >> 4;
  __shared__ alignas(16) u16 sK[2][64 * 64];   // [s][d], 16B-granule XOR swizzle
  __shared__ alignas(16) u16 sV[2][64 * 64];   // [d][s], same swizzle
  __shared__ alignas(16) u16 sP[4][16 * 72];   // per-wave P [16q][64s] +8 pad

  // Q fragments (A-frag rows = lr), d-halves 0..31 / 32..63
  const size_t qrow = (size_t)(b * 2048 + q0 + w * 16 + lr) * 2048 + h * 64;
  const bf16x8 aq0 = ldbf8(qk + qrow + lg * 8);
  const bf16x8 aq1 = ldbf8(qk + qrow + 32 + lg * 8);

  float m_i[4], l_i[4];
  f32x4 acc[4];
#pragma unroll
  for (int r = 0; r < 4; ++r) { m_i[r] = -1e30f; l_i[r] = 0.f; }
#pragma unroll
  for (int dn = 0; dn < 4; ++dn) acc[dn] = f32x4{0.f, 0.f, 0.f, 0.f};

  // stage tile: K rows s (128B), V rows d (128B); src col8 pre-swizzled so a
  // linear LDS write yields lds[row][col8 ^ (row&7)] -> conflict-free reads.
  auto stage = [&](int buf, int s0) {
#pragma unroll
    for (int i = 0; i < 2; ++i) {
      const int c = w * 2 + i;
      const int g = c * 64 + lane;
      const int row = g >> 3;
      const int cs = (g & 7) ^ (row & 7);
      gll16(qk + (size_t)(b * 2048 + s0 + row) * 2048 + 1024 + h * 64 + cs * 8,
            &sK[buf][c * 512]);
      gll16(vt + (size_t)(h * 64 + row) * 4096 + b * 2048 + s0 + cs * 8,
            &sV[buf][c * 512]);
    }
  };

  const int nt = qb + 1;
  stage(0, 0);
  constexpr float SC = 0.03125f * 1.44269504088896341f;  // C^-0.5 * log2(e)

  for (int t = 0; t < nt; ++t) {
    const int buf = t & 1;
    if (t + 1 < nt) {
      stage(buf ^ 1, (t + 1) * 64);
      asm volatile("s_waitcnt vmcnt(4)" ::: "memory");  // current tile landed
    } else {
      asm volatile("s_waitcnt vmcnt(0)" ::: "memory");
    }
    __builtin_amdgcn_s_barrier();
    asm volatile("" ::: "memory");

    const u16* Kb = sK[buf];
    const u16* Vb = sV[buf];
    // S[16q x 64s] = Q . K^T  (D row = q local lg*4+r, col = s = sn*16+lr)
    f32x4 sf[4];
#pragma unroll
    for (int sn = 0; sn < 4; ++sn) {
      const int row = sn * 16 + lr;
      const int x7 = lr & 7;
      bf16x8 k0f = ldbf8(&Kb[row * 64 + ((lg ^ x7) * 8)]);
      bf16x8 k1f = ldbf8(&Kb[row * 64 + (((4 + lg) ^ x7) * 8)]);
      f32x4 z = {0.f, 0.f, 0.f, 0.f};
      z = MFMA16(aq0, k0f, z, 0, 0, 0);
      z = MFMA16(aq1, k1f, z, 0, 0, 0);
      sf[sn] = z;
    }

    const bool maskt = (t == nt - 1);
#pragma unroll
    for (int r = 0; r < 4; ++r) {  // online softmax (exp2 domain)
      float v0 = sf[0][r] * SC, v1 = sf[1][r] * SC, v2 = sf[2][r] * SC, v3 = sf[3][r] * SC;
      if (maskt) {
        const int ql = w * 16 + lg * 4 + r;
        if (lr > ql)      v0 = -1e30f;
        if (16 + lr > ql) v1 = -1e30f;
        if (32 + lr > ql) v2 = -1e30f;
        if (48 + lr > ql) v3 = -1e30f;
      }
      float mx = fmaxf(fmaxf(v0, v1), fmaxf(v2, v3));
      mx = fmaxf(mx, __shfl_xor(mx, 1, 16));
      mx = fmaxf(mx, __shfl_xor(mx, 2, 16));
      mx = fmaxf(mx, __shfl_xor(mx, 4, 16));
      mx = fmaxf(mx, __shfl_xor(mx, 8, 16));
      const float mnew = fmaxf(m_i[r], mx);
      const float al = exp2f(m_i[r] - mnew);
      const float p0 = exp2f(v0 - mnew), p1 = exp2f(v1 - mnew);
      const float p2 = exp2f(v2 - mnew), p3 = exp2f(v3 - mnew);
      float rs = (p0 + p1) + (p2 + p3);
      rs += __shfl_xor(rs, 1, 16);
      rs += __shfl_xor(rs, 2, 16);
      rs += __shfl_xor(rs, 4, 16);
      rs += __shfl_xor(rs, 8, 16);
      l_i[r] = l_i[r] * al + rs;
      m_i[r] = mnew;
      acc[0][r] *= al; acc[1][r] *= al; acc[2][r] *= al; acc[3][r] *= al;
      const int pr = (lg * 4 + r) * 72;
      sP[w][pr + lr] = f2bf(p0);
      sP[w][pr + 16 + lr] = f2bf(p1);
      sP[w][pr + 32 + lr] = f2bf(p2);
      sP[w][pr + 48 + lr] = f2bf(p3);
    }

    // O += P . V   (wave-local P; compiler inserts lgkmcnt for the RAW)
    const bf16x8 pa0 = ldbf8(&sP[w][lr * 72 + lg * 8]);
    const bf16x8 pa1 = ldbf8(&sP[w][lr * 72 + 32 + lg * 8]);
#pragma unroll
    for (int dn = 0; dn < 4; ++dn) {
      const int row = dn * 16 + lr;
      const int x7 = lr & 7;
      bf16x8 v0f = ldbf8(&Vb[row * 64 + ((lg ^ x7) * 8)]);
      bf16x8 v1f = ldbf8(&Vb[row * 64 + (((4 + lg) ^ x7) * 8)]);
      acc[dn] = MFMA16(pa0, v0f, acc[dn], 0, 0, 0);
      acc[dn] = MFMA16(pa1, v1f, acc[dn], 0, 0, 0);
    }
    asm volatile("" ::: "memory");
    __builtin_amdgcn_s_barrier();  // WAR guard before next stage overwrites
    asm volatile("" ::: "memory");
  }

  const int trow = q0 + w * 16 + lg * 4;
#pragma unroll
  for (int r = 0; r < 4; ++r) {
    const float inv = 1.0f / l_i[r];
#pragma unroll
    for (int dn = 0; dn < 4; ++dn) {
      const size_t idx = ((size_t)(b * 2048 + trow + r)) * 1024 + h * 64 + dn * 16 + lr;
      x2[idx] = x[idx] + acc[dn][r] * inv;
    }
  }
}

// ---------------------------------------------------------------------------
extern "C" void kernel_launch(void* const* d_in, const int* in_sizes, int n_in,
                              void* d_out, int out_size, void* d_ws, size_t ws_size,
                              hipStream_t stream) {
  const float* x   = (const float*)d_in[0];
  const float* Wq  = (const float*)d_in[1];
  const float* Wk  = (const float*)d_in[2];
  const float* Wv  = (const float*)d_in[3];
  const float* W1  = (const float*)d_in[4];
  const float* b1  = (const float*)d_in[5];
  const float* W2  = (const float*)d_in[6];
  const float* b2  = (const float*)d_in[7];
  const float* g1  = (const float*)d_in[8];
  const float* be1 = (const float*)d_in[9];
  const float* g2  = (const float*)d_in[10];
  const float* be2 = (const float*)d_in[11];
  float* out = (float*)d_out;

  char* ws = (char*)d_ws;
  size_t off = 0;
  auto alloc = [&](size_t bytes) { char* p = ws + off; off += (bytes + 255) & ~(size_t)255; return p; };
  u16*    qkb   = (u16*)alloc(4096ull * 2048 * 2);   // [tok][Q|K]          16MB
  u16*    vtb   = (u16*)alloc(1024ull * 4096 * 2);   // [hd][tok]            8MB
  (void)alloc(4096ull * 1024 * 2);                   // h1 overflow region   8MB
  u16*    h1    = qkb;                               // MLP1 out aliases qk+vt+overflow (32MB)
  float*  x2    = (float*)alloc(4096ull * 1024 * 4); // x + attn            16MB
  u16*    hbuf  = (u16*)alloc(4096ull * 1024 * 2);   // LN outputs           8MB
  u16*    wqkvt = (u16*)alloc(3072ull * 1024 * 2);
  u16*    w1t   = (u16*)alloc(4096ull * 1024 * 2);
  u16*    w2t   = (u16*)alloc(1024ull * 4096 * 2);
  float2* part  = (float2*)alloc(2048ull * 8 * 8);
  float2* stats = (float2*)alloc(2048ull * 8);
  (void)ws_size; (void)in_sizes; (void)n_in; (void)out_size;

  // weight prep (bf16, B-transposed)
  transpose_head<<<dim3(16, 16), 256, 0, stream>>>(Wq, wqkvt, 0);
  transpose_head<<<dim3(16, 16), 256, 0, stream>>>(Wk, wqkvt, 1024);
  transpose_head<<<dim3(16, 16), 256, 0, stream>>>(Wv, wqkvt, 2048);
  transpose_big<<<dim3(16, 64), 256, 0, stream>>>(W1, w1t, 1024, 4096);
  transpose_big<<<dim3(64, 16), 256, 0, stream>>>(W2, w2t, 4096, 1024);

  // LN1 (over T) -> hbuf
  ln_partial<<<dim3(32, 8), 256, 0, stream>>>(x, part);
  ln_stats<<<8, 256, 0, stream>>>(part, stats);
  ln_apply<<<4096, 256, 0, stream>>>(x, stats, g1, be1, hbuf);

  // QK GEMM: [4096,1024] x W_qk^T -> qkb [4096][2048]
  gemm_kernel<4, 4, 0><<<dim3(16, 32), 256, 0, stream>>>(hbuf, wqkvt, qkb, nullptr, nullptr, nullptr, 2048, 1024);
  // V^T GEMM: Wv^T [1024,1024] x LN1^T -> vtb [1024][4096]
  gemm_kernel<4, 4, 0><<<dim3(32, 8), 256, 0, stream>>>(wqkvt + 2048 * 1024, hbuf, vtb, nullptr, nullptr, nullptr, 4096, 1024);

  // attention + residual -> x2 (f32)
  attn_kernel<<<dim3(32, 32), 256, 0, stream>>>(qkb, vtb, x, x2);

  // LN2 (over T) -> hbuf
  ln_partial<<<dim3(32, 8), 256, 0, stream>>>(x2, part);
  ln_stats<<<8, 256, 0, stream>>>(part, stats);
  ln_apply<<<4096, 256, 0, stream>>>(x2, stats, g2, be2, hbuf);

  // MLP1: relu(h @ W1 + b1) -> h1 (bf16 [4096][4096])
  gemm_kernel<4, 4, 1><<<dim3(32, 32), 256, 0, stream>>>(hbuf, w1t, h1, nullptr, b1, nullptr, 4096, 1024);

  // MLP2: x2 + h1 @ W2 + b2 -> out (f32)
  gemm_kernel<4, 2, 2><<<dim3(16, 32), 256, 0, stream>>>(h1, w2t, nullptr, out, b2, x2, 1024, 4096);
}

// Round 3
// 324.374 us; speedup vs baseline: 1.4031x; 1.1422x over previous
//
#include <hip/hip_runtime.h>

// ---------------------------------------------------------------------------
// Transformer block on MI355X (gfx950), bf16 MFMA pipeline, fp32 residual/LN.
//   x:[2,2048,1024]  LN over T (ddof=1) -> QK GEMM + V^T GEMM -> causal flash
//   attn (split-s flash-decoding, dbuf LDS, swizzled global_load_lds) + merge
//   -> +resid -> LN -> MLP -> +resid
// ---------------------------------------------------------------------------

typedef __bf16 bf16x8 __attribute__((ext_vector_type(8)));
typedef float f32x4 __attribute__((ext_vector_type(4)));
typedef unsigned short u16;
typedef u16 u16x8 __attribute__((ext_vector_type(8)));
typedef u16 u16x4 __attribute__((ext_vector_type(4)));

#define MFMA16 __builtin_amdgcn_mfma_f32_16x16x32_bf16

__device__ __forceinline__ u16 f2bf(float f) {  // native v_cvt (RNE)
  return __builtin_bit_cast(u16, (__bf16)f);
}
__device__ __forceinline__ float bf2f(u16 u) {
  return __builtin_bit_cast(float, (unsigned)u << 16);
}
__device__ __forceinline__ bf16x8 ldbf8(const u16* p) {
  return __builtin_bit_cast(bf16x8, *reinterpret_cast<const u16x8*>(p));
}
// async global->LDS, 16B per lane, dest = wave-uniform base + lane*16
__device__ __forceinline__ void gll16(const void* g, void* l) {
  __builtin_amdgcn_global_load_lds((const __attribute__((address_space(1))) void*)g,
                                   (__attribute__((address_space(3))) void*)l, 16, 0, 0);
}

// ---------------- weight transpose (f32 [K][N] -> bf16 [N][K]) -------------
__global__ __launch_bounds__(256) void transpose_big(const float* __restrict__ in,
                                                     u16* __restrict__ out, int K, int N) {
  __shared__ float tile[64][65];
  const int k0 = blockIdx.x * 64, n0 = blockIdx.y * 64;
  const int c = threadIdx.x & 63, rg = threadIdx.x >> 6;
#pragma unroll
  for (int i = 0; i < 16; ++i) {
    int r = rg * 16 + i;
    tile[r][c] = in[(size_t)(k0 + r) * N + n0 + c];
  }
  __syncthreads();
#pragma unroll
  for (int i = 0; i < 16; ++i) {
    int nl = rg * 16 + i;
    out[(size_t)(n0 + nl) * K + k0 + c] = f2bf(tile[c][nl]);
  }
}

// Wq/Wk/Wv: [H][1024][64] f32 -> rows (zoff + h*64 + d) of [3072][1024] bf16
__global__ __launch_bounds__(256) void transpose_head(const float* __restrict__ W,
                                                      u16* __restrict__ out, int zoff) {
  __shared__ float tile[64][65];
  const int k0 = blockIdx.x * 64, h = blockIdx.y;
  const float* in = W + (size_t)h * 1024 * 64;
  const int c = threadIdx.x & 63, rg = threadIdx.x >> 6;
#pragma unroll
  for (int i = 0; i < 16; ++i) {
    int r = rg * 16 + i;
    tile[r][c] = in[(size_t)(k0 + r) * 64 + c];
  }
  __syncthreads();
#pragma unroll
  for (int i = 0; i < 16; ++i) {
    int nl = rg * 16 + i;
    out[(size_t)(zoff + h * 64 + nl) * 1024 + k0 + c] = f2bf(tile[c][nl]);
  }
}

// ---------------- LayerNorm over sequence axis T (per (b,c)) ---------------
__global__ __launch_bounds__(256) void ln_partial(const float* __restrict__ x,
                                                  float2* __restrict__ part) {
  const int b = blockIdx.x >> 4, c0 = (blockIdx.x & 15) * 64;
  const int c = c0 + (threadIdx.x & 63), tg = threadIdx.x >> 6;
  const int t0 = blockIdx.y * 256 + tg * 64;
  float s = 0.f, sq = 0.f;
  const float* p = x + (size_t)(b * 2048 + t0) * 1024 + c;
#pragma unroll 8
  for (int i = 0; i < 64; ++i) {
    float v = p[(size_t)i * 1024];
    s += v; sq += v * v;
  }
  __shared__ float ss[256], sb[256];
  ss[threadIdx.x] = s; sb[threadIdx.x] = sq;
  __syncthreads();
  if (threadIdx.x < 64) {
    s  = ss[threadIdx.x] + ss[threadIdx.x + 64] + ss[threadIdx.x + 128] + ss[threadIdx.x + 192];
    sq = sb[threadIdx.x] + sb[threadIdx.x + 64] + sb[threadIdx.x + 128] + sb[threadIdx.x + 192];
    part[(size_t)(b * 1024 + c) * 8 + blockIdx.y] = make_float2(s, sq);
  }
}

__global__ __launch_bounds__(256) void ln_stats(const float2* __restrict__ part,
                                                float2* __restrict__ stats) {
  const int bc = blockIdx.x * 256 + threadIdx.x;
  float s = 0.f, sq = 0.f;
#pragma unroll
  for (int i = 0; i < 8; ++i) {
    float2 v = part[(size_t)bc * 8 + i];
    s += v.x; sq += v.y;
  }
  const float mean = s * (1.0f / 2048.0f);
  const float var = (sq - 2048.0f * mean * mean) * (1.0f / 2047.0f);  // ddof=1
  stats[bc] = make_float2(mean, rsqrtf(var + 1e-5f));
}

__global__ __launch_bounds__(256) void ln_apply(const float* __restrict__ x,
                                                const float2* __restrict__ stats,
                                                const float* __restrict__ g,
                                                const float* __restrict__ be,
                                                u16* __restrict__ out) {
  const size_t flat = ((size_t)blockIdx.x * 256 + threadIdx.x) * 4;
  const int b = (int)(flat >> 21);
  const int c = (int)(flat & 1023);
  float4 xv = *reinterpret_cast<const float4*>(x + flat);
  float vs[4] = {xv.x, xv.y, xv.z, xv.w};
  u16x4 o;
#pragma unroll
  for (int j = 0; j < 4; ++j) {
    float2 st = stats[b * 1024 + c + j];
    o[j] = f2bf(g[c + j] * (vs[j] - st.x) * st.y + be[c + j]);
  }
  *reinterpret_cast<u16x4*>(out + flat) = o;
}

// ---------------- GEMM (m97 structure): C = A[M,K] x Bt[N,K]^T -------------
// EPI 0: store bf16.  1: +bias, ReLU, bf16.  2: +bias +resid, f32.
template <int MI, int NI, int EPI>
__global__ __launch_bounds__(256) void gemm_kernel(const u16* __restrict__ A,
                                                   const u16* __restrict__ Bt,
                                                   u16* __restrict__ outb,
                                                   float* __restrict__ outf,
                                                   const float* __restrict__ bias,
                                                   const float* __restrict__ resid,
                                                   int N, int K) {
  constexpr int BM = MI * 32, BN = NI * 32;   // 2x2 waves per block
  __shared__ alignas(16) u16 sA[BM * 32];
  __shared__ alignas(16) u16 sB[BN * 32];
  const int n0 = blockIdx.x * BN, m0 = blockIdx.y * BM;
  const int tid = threadIdx.x, lane = tid & 63, wid = tid >> 6;
  const int wm = (wid >> 1) * (MI * 16), wn = (wid & 1) * (NI * 16);
  const int lr = lane & 15, lg = lane >> 4;
  constexpr int CA = BM / 64;
  constexpr int CB = BN / 64;
  f32x4 acc[MI][NI] = {};

  for (int k0 = 0; k0 < K; k0 += 32) {
    __syncthreads();  // WAR: prior iteration's frag reads complete
#pragma unroll
    for (int i = 0; i < CA; ++i) {
      const int c = wid * CA + i, g = c * 64 + lane;
      gll16(A + (size_t)(m0 + (g >> 2)) * K + k0 + (g & 3) * 8, &sA[c * 512]);
    }
#pragma unroll
    for (int i = 0; i < CB; ++i) {
      const int c = wid * CB + i, g = c * 64 + lane;
      gll16(Bt + (size_t)(n0 + (g >> 2)) * K + k0 + (g & 3) * 8, &sB[c * 512]);
    }
    __syncthreads();  // drains vmcnt -> tile visible to all waves
    bf16x8 af[MI], bfr[NI];
#pragma unroll
    for (int mi = 0; mi < MI; ++mi) af[mi] = ldbf8(&sA[(wm + mi * 16 + lr) * 32 + lg * 8]);
#pragma unroll
    for (int ni = 0; ni < NI; ++ni) bfr[ni] = ldbf8(&sB[(wn + ni * 16 + lr) * 32 + lg * 8]);
#pragma unroll
    for (int mi = 0; mi < MI; ++mi)
#pragma unroll
      for (int ni = 0; ni < NI; ++ni)
        acc[mi][ni] = MFMA16(af[mi], bfr[ni], acc[mi][ni], 0, 0, 0);
  }

#pragma unroll
  for (int mi = 0; mi < MI; ++mi)
#pragma unroll
    for (int ni = 0; ni < NI; ++ni)
#pragma unroll
      for (int r = 0; r < 4; ++r) {
        const int row = m0 + wm + mi * 16 + lg * 4 + r;   // C/D: row=(lane>>4)*4+reg
        const int col = n0 + wn + ni * 16 + lr;           //      col=lane&15
        float v = acc[mi][ni][r];
        if (EPI == 0) {
          outb[(size_t)row * N + col] = f2bf(v);
        } else if (EPI == 1) {
          v += bias[col];
          v = fmaxf(v, 0.f);
          outb[(size_t)row * N + col] = f2bf(v);
        } else {
          v += bias[col] + resid[(size_t)row * N + col];
          outf[(size_t)row * N + col] = v;
        }
      }
}

// ---------------- causal flash attention: split-s partial pass -------------
// qk: bf16 [4096 tok][2048] (Q|K per head).  vt: bf16 [1024 hd][4096 tok].
// blockIdx.x in [0,80): chunk id (reversed -> heaviest first). Each block
// covers tiles [t0,t1) of (qb+1) total KVBLK=64 tiles; writes unnormalized
// partial O (bf16) + per-row (m,l) in exp2 domain.
__global__ __launch_bounds__(256) void attn_partial(const u16* __restrict__ qk,
                                                    const u16* __restrict__ vt,
                                                    u16* __restrict__ Opart,
                                                    float2* __restrict__ ml) {
  const int xr = 79 - (int)blockIdx.x;  // heavy (4-chunk qb) dispatched first
  int qb, ch, nc;
  if (xr < 8)       { qb = xr;                ch = 0;            nc = 1; }
  else if (xr < 24) { qb = 8 + ((xr - 8) >> 1);  ch = (xr - 8) & 1;  nc = 2; }
  else if (xr < 48) { qb = 16 + (xr - 24) / 3;   ch = (xr - 24) % 3; nc = 3; }
  else              { qb = 24 + ((xr - 48) >> 2); ch = (xr - 48) & 3; nc = 4; }
  const int nt_tot = qb + 1;
  const int t0 = (ch * nt_tot) / nc;
  const int t1 = ((ch + 1) * nt_tot) / nc;
  const int bh = blockIdx.y, b = bh >> 4, h = bh & 15;
  const int slot = bh * 80 + xr;
  const int q0 = qb * 64;
  const int tid = threadIdx.x, lane = tid & 63, w = tid >> 6;
  const int lr = lane & 15, lg = lane >> 4;
  __shared__ alignas(16) u16 sK[2][64 * 64];   // [s][d], 16B-granule XOR swizzle
  __shared__ alignas(16) u16 sV[2][64 * 64];   // [d][s], same swizzle
  __shared__ alignas(16) u16 sP[4][16 * 64];   // per-wave P, XOR-swizzled

  const size_t qrow = (size_t)(b * 2048 + q0 + w * 16 + lr) * 2048 + h * 64;
  const bf16x8 aq0 = ldbf8(qk + qrow + lg * 8);
  const bf16x8 aq1 = ldbf8(qk + qrow + 32 + lg * 8);

  float m_i[4], l_i[4];
  f32x4 acc[4];
#pragma unroll
  for (int r = 0; r < 4; ++r) { m_i[r] = -1e30f; l_i[r] = 0.f; }
#pragma unroll
  for (int dn = 0; dn < 4; ++dn) acc[dn] = f32x4{0.f, 0.f, 0.f, 0.f};

  auto stage = [&](int buf, int s0) {
#pragma unroll
    for (int i = 0; i < 2; ++i) {
      const int c = w * 2 + i;
      const int g = c * 64 + lane;
      const int row = g >> 3;
      const int cs = (g & 7) ^ (row & 7);
      gll16(qk + (size_t)(b * 2048 + s0 + row) * 2048 + 1024 + h * 64 + cs * 8,
            &sK[buf][c * 512]);
      gll16(vt + (size_t)(h * 64 + row) * 4096 + b * 2048 + s0 + cs * 8,
            &sV[buf][c * 512]);
    }
  };

  stage(0, t0 * 64);
  constexpr float SC = 0.03125f * 1.44269504088896341f;  // C^-0.5 * log2(e)

  for (int t = t0; t < t1; ++t) {
    const int buf = (t - t0) & 1;
    if (t + 1 < t1) {
      stage(buf ^ 1, (t + 1) * 64);
      asm volatile("s_waitcnt vmcnt(4)" ::: "memory");
    } else {
      asm volatile("s_waitcnt vmcnt(0)" ::: "memory");
    }
    __builtin_amdgcn_s_barrier();
    asm volatile("" ::: "memory");

    const u16* Kb = sK[buf];
    const u16* Vb = sV[buf];
    f32x4 sf[4];
    __builtin_amdgcn_s_setprio(1);
#pragma unroll
    for (int sn = 0; sn < 4; ++sn) {  // S[16q x 64s] = Q . K^T
      const int row = sn * 16 + lr;
      const int x7 = lr & 7;
      bf16x8 k0f = ldbf8(&Kb[row * 64 + ((lg ^ x7) * 8)]);
      bf16x8 k1f = ldbf8(&Kb[row * 64 + (((4 + lg) ^ x7) * 8)]);
      f32x4 z = {0.f, 0.f, 0.f, 0.f};
      z = MFMA16(aq0, k0f, z, 0, 0, 0);
      z = MFMA16(aq1, k1f, z, 0, 0, 0);
      sf[sn] = z;
    }
    __builtin_amdgcn_s_setprio(0);

    const bool maskt = (t == nt_tot - 1);
    const int x7p = lr & 7;
#pragma unroll
    for (int r = 0; r < 4; ++r) {  // online softmax (exp2 domain)
      float v0 = sf[0][r] * SC, v1 = sf[1][r] * SC, v2 = sf[2][r] * SC, v3 = sf[3][r] * SC;
      if (maskt) {
        const int ql = w * 16 + lg * 4 + r;
        if (lr > ql)      v0 = -1e30f;
        if (16 + lr > ql) v1 = -1e30f;
        if (32 + lr > ql) v2 = -1e30f;
        if (48 + lr > ql) v3 = -1e30f;
      }
      float mx = fmaxf(fmaxf(v0, v1), fmaxf(v2, v3));
      mx = fmaxf(mx, __shfl_xor(mx, 1, 16));
      mx = fmaxf(mx, __shfl_xor(mx, 2, 16));
      mx = fmaxf(mx, __shfl_xor(mx, 4, 16));
      mx = fmaxf(mx, __shfl_xor(mx, 8, 16));
      const float mnew = fmaxf(m_i[r], mx);
      const float al = exp2f(m_i[r] - mnew);
      const float p0 = exp2f(v0 - mnew), p1 = exp2f(v1 - mnew);
      const float p2 = exp2f(v2 - mnew), p3 = exp2f(v3 - mnew);
      float rs = (p0 + p1) + (p2 + p3);
      rs += __shfl_xor(rs, 1, 16);
      rs += __shfl_xor(rs, 2, 16);
      rs += __shfl_xor(rs, 4, 16);
      rs += __shfl_xor(rs, 8, 16);
      l_i[r] = l_i[r] * al + rs;
      m_i[r] = mnew;
      acc[0][r] *= al; acc[1][r] *= al; acc[2][r] *= al; acc[3][r] *= al;
      const int prow = lg * 4 + r;
      const int pb = prow * 64, px = prow & 7;
      sP[w][pb + (((lr >> 3) ^ px) * 8) + (lr & 7)]       = f2bf(p0);
      sP[w][pb + (((2 + (lr >> 3)) ^ px) * 8) + (lr & 7)] = f2bf(p1);
      sP[w][pb + (((4 + (lr >> 3)) ^ px) * 8) + (lr & 7)] = f2bf(p2);
      sP[w][pb + (((6 + (lr >> 3)) ^ px) * 8) + (lr & 7)] = f2bf(p3);
    }

    // O += P . V   (wave-local P; compiler inserts lgkmcnt for the RAW)
    const bf16x8 pa0 = ldbf8(&sP[w][lr * 64 + ((lg ^ x7p) * 8)]);
    const bf16x8 pa1 = ldbf8(&sP[w][lr * 64 + (((4 + lg) ^ x7p) * 8)]);
    __builtin_amdgcn_s_setprio(1);
#pragma unroll
    for (int dn = 0; dn < 4; ++dn) {
      const int row = dn * 16 + lr;
      bf16x8 v0f = ldbf8(&Vb[row * 64 + ((lg ^ x7p) * 8)]);
      bf16x8 v1f = ldbf8(&Vb[row * 64 + (((4 + lg) ^ x7p) * 8)]);
      acc[dn] = MFMA16(pa0, v0f, acc[dn], 0, 0, 0);
      acc[dn] = MFMA16(pa1, v1f, acc[dn], 0, 0, 0);
    }
    __builtin_amdgcn_s_setprio(0);
    asm volatile("" ::: "memory");
    __builtin_amdgcn_s_barrier();  // WAR guard before next stage overwrites
    asm volatile("" ::: "memory");
  }

  // partial epilogue: unnormalized O (bf16) + (m,l) per row
  const int rbase = w * 16 + lg * 4;
#pragma unroll
  for (int r = 0; r < 4; ++r) {
    const int row = rbase + r;
    if (lr == 0) ml[(size_t)slot * 64 + row] = make_float2(m_i[r], l_i[r]);
#pragma unroll
    for (int dn = 0; dn < 4; ++dn)
      Opart[((size_t)slot * 64 + row) * 64 + dn * 16 + lr] = f2bf(acc[dn][r]);
  }
}

// ---------------- attention merge + residual -------------------------------
__global__ __launch_bounds__(256) void attn_merge(const u16* __restrict__ Opart,
                                                  const float2* __restrict__ ml,
                                                  const float* __restrict__ x,
                                                  float* __restrict__ x2) {
  const int qb = blockIdx.x, bh = blockIdx.y, b = bh >> 4, h = bh & 15;
  int nc, s0;
  if (qb < 8)       { nc = 1; s0 = qb; }
  else if (qb < 16) { nc = 2; s0 = 8 + (qb - 8) * 2; }
  else if (qb < 24) { nc = 3; s0 = 24 + (qb - 16) * 3; }
  else              { nc = 4; s0 = 48 + (qb - 24) * 4; }
  const size_t slot0 = (size_t)bh * 80 + s0;
  const int tid = threadIdx.x;
  const int row = tid >> 2, d0 = (tid & 3) * 16;

  float wgt[4];
  float mmax = -1e30f, lsum = 0.f;
  for (int i = 0; i < nc; ++i) {
    float2 v = ml[(slot0 + i) * 64 + row];
    wgt[i] = v.x;
    mmax = fmaxf(mmax, v.x);
  }
  for (int i = 0; i < nc; ++i) {
    float2 v = ml[(slot0 + i) * 64 + row];
    wgt[i] = exp2f(wgt[i] - mmax);
    lsum += wgt[i] * v.y;
  }
  const float inv = 1.0f / lsum;

#pragma unroll
  for (int half = 0; half < 2; ++half) {
    const int d = d0 + half * 8;
    float o[8] = {0.f, 0.f, 0.f, 0.f, 0.f, 0.f, 0.f, 0.f};
    for (int i = 0; i < nc; ++i) {
      u16x8 v = *reinterpret_cast<const u16x8*>(&Opart[((slot0 + i) * 64 + row) * 64 + d]);
#pragma unroll
      for (int j = 0; j < 8; ++j) o[j] += wgt[i] * bf2f(v[j]);
    }
    const size_t idx = ((size_t)(b * 2048 + qb * 64 + row)) * 1024 + h * 64 + d;
    float4 x0 = *reinterpret_cast<const float4*>(x + idx);
    float4 x1 = *reinterpret_cast<const float4*>(x + idx + 4);
    float4 o0 = make_float4(x0.x + o[0] * inv, x0.y + o[1] * inv, x0.z + o[2] * inv, x0.w + o[3] * inv);
    float4 o1 = make_float4(x1.x + o[4] * inv, x1.y + o[5] * inv, x1.z + o[6] * inv, x1.w + o[7] * inv);
    *reinterpret_cast<float4*>(x2 + idx) = o0;
    *reinterpret_cast<float4*>(x2 + idx + 4) = o1;
  }
}

// ---------------------------------------------------------------------------
extern "C" void kernel_launch(void* const* d_in, const int* in_sizes, int n_in,
                              void* d_out, int out_size, void* d_ws, size_t ws_size,
                              hipStream_t stream) {
  const float* x   = (const float*)d_in[0];
  const float* Wq  = (const float*)d_in[1];
  const float* Wk  = (const float*)d_in[2];
  const float* Wv  = (const float*)d_in[3];
  const float* W1  = (const float*)d_in[4];
  const float* b1  = (const float*)d_in[5];
  const float* W2  = (const float*)d_in[6];
  const float* b2  = (const float*)d_in[7];
  const float* g1  = (const float*)d_in[8];
  const float* be1 = (const float*)d_in[9];
  const float* g2  = (const float*)d_in[10];
  const float* be2 = (const float*)d_in[11];
  float* out = (float*)d_out;

  char* ws = (char*)d_ws;
  size_t off = 0;
  auto alloc = [&](size_t bytes) { char* p = ws + off; off += (bytes + 255) & ~(size_t)255; return p; };
  u16*    qkb   = (u16*)alloc(4096ull * 2048 * 2);   // [tok][Q|K]          16MB
  u16*    vtb   = (u16*)alloc(1024ull * 4096 * 2);   // [hd][tok]            8MB
  (void)alloc(4096ull * 1024 * 2);                   // h1 overflow region   8MB
  u16*    h1    = qkb;                               // MLP1 out aliases qk+vt+overflow (32MB)
  float*  x2    = (float*)alloc(4096ull * 1024 * 4); // x + attn            16MB
  u16*    hbuf  = (u16*)alloc(4096ull * 1024 * 2);   // LN outputs           8MB
  u16*    wqkvt = (u16*)alloc(3072ull * 1024 * 2);
  u16*    w1t   = (u16*)alloc(4096ull * 1024 * 2);
  u16*    w2t   = (u16*)alloc(1024ull * 4096 * 2);
  float2* part  = (float2*)alloc(2048ull * 8 * 8);
  float2* stats = (float2*)alloc(2048ull * 8);
  u16*    Opart = (u16*)alloc(32ull * 80 * 64 * 64 * 2);   // ~21MB
  float2* ml    = (float2*)alloc(32ull * 80 * 64 * 8);     // ~1.3MB
  (void)ws_size; (void)in_sizes; (void)n_in; (void)out_size;

  // weight prep (bf16, B-transposed)
  transpose_head<<<dim3(16, 16), 256, 0, stream>>>(Wq, wqkvt, 0);
  transpose_head<<<dim3(16, 16), 256, 0, stream>>>(Wk, wqkvt, 1024);
  transpose_head<<<dim3(16, 16), 256, 0, stream>>>(Wv, wqkvt, 2048);
  transpose_big<<<dim3(16, 64), 256, 0, stream>>>(W1, w1t, 1024, 4096);
  transpose_big<<<dim3(64, 16), 256, 0, stream>>>(W2, w2t, 4096, 1024);

  // LN1 (over T) -> hbuf
  ln_partial<<<dim3(32, 8), 256, 0, stream>>>(x, part);
  ln_stats<<<8, 256, 0, stream>>>(part, stats);
  ln_apply<<<4096, 256, 0, stream>>>(x, stats, g1, be1, hbuf);

  // QK GEMM: [4096,1024] x W_qk^T -> qkb [4096][2048]
  gemm_kernel<4, 4, 0><<<dim3(16, 32), 256, 0, stream>>>(hbuf, wqkvt, qkb, nullptr, nullptr, nullptr, 2048, 1024);
  // V^T GEMM: Wv^T [1024,1024] x LN1^T -> vtb [1024][4096]
  gemm_kernel<4, 4, 0><<<dim3(32, 8), 256, 0, stream>>>(wqkvt + 2048 * 1024, hbuf, vtb, nullptr, nullptr, nullptr, 4096, 1024);

  // attention: split-s partials, then merge + residual -> x2 (f32)
  attn_partial<<<dim3(80, 32), 256, 0, stream>>>(qkb, vtb, Opart, ml);
  attn_merge<<<dim3(32, 32), 256, 0, stream>>>(Opart, ml, x, x2);

  // LN2 (over T) -> hbuf
  ln_partial<<<dim3(32, 8), 256, 0, stream>>>(x2, part);
  ln_stats<<<8, 256, 0, stream>>>(part, stats);
  ln_apply<<<4096, 256, 0, stream>>>(x2, stats, g2, be2, hbuf);

  // MLP1: relu(h @ W1 + b1) -> h1 (bf16 [4096][4096])
  gemm_kernel<4, 4, 1><<<dim3(32, 32), 256, 0, stream>>>(hbuf, w1t, h1, nullptr, b1, nullptr, 4096, 1024);

  // MLP2: x2 + h1 @ W2 + b2 -> out (f32)
  gemm_kernel<4, 2, 2><<<dim3(16, 32), 256, 0, stream>>>(h1, w2t, nullptr, out, b2, x2, 1024, 4096);
}

// Round 4
// 308.769 us; speedup vs baseline: 1.4740x; 1.0505x over previous
//
#include <hip/hip_runtime.h>

// ---------------------------------------------------------------------------
// Transformer block on MI355X (gfx950), bf16 MFMA pipeline, fp32 residual/LN.
//   x:[2,2048,1024]  LN over T (ddof=1) -> QK GEMM + V^T GEMM -> causal flash
//   attn (split-s flash-decoding, dbuf LDS, swizzled global_load_lds) + merge
//   -> +resid -> LN -> MLP -> +resid
// GEMMs: double-buffered 2-phase (T3-minimum) + XCD-aware block swizzle (T1).
// Attn: defer-max rescale threshold (T13).
// ---------------------------------------------------------------------------

typedef __bf16 bf16x8 __attribute__((ext_vector_type(8)));
typedef float f32x4 __attribute__((ext_vector_type(4)));
typedef unsigned short u16;
typedef u16 u16x8 __attribute__((ext_vector_type(8)));
typedef u16 u16x4 __attribute__((ext_vector_type(4)));

#define MFMA16 __builtin_amdgcn_mfma_f32_16x16x32_bf16

__device__ __forceinline__ u16 f2bf(float f) {  // native v_cvt (RNE)
  return __builtin_bit_cast(u16, (__bf16)f);
}
__device__ __forceinline__ float bf2f(u16 u) {
  return __builtin_bit_cast(float, (unsigned)u << 16);
}
__device__ __forceinline__ bf16x8 ldbf8(const u16* p) {
  return __builtin_bit_cast(bf16x8, *reinterpret_cast<const u16x8*>(p));
}
// async global->LDS, 16B per lane, dest = wave-uniform base + lane*16
__device__ __forceinline__ void gll16(const void* g, void* l) {
  __builtin_amdgcn_global_load_lds((const __attribute__((address_space(1))) void*)g,
                                   (__attribute__((address_space(3))) void*)l, 16, 0, 0);
}

// ---------------- weight transpose (f32 [K][N] -> bf16 [N][K]) -------------
__global__ __launch_bounds__(256) void transpose_big(const float* __restrict__ in,
                                                     u16* __restrict__ out, int K, int N) {
  __shared__ float tile[64][65];
  const int k0 = blockIdx.x * 64, n0 = blockIdx.y * 64;
  const int c = threadIdx.x & 63, rg = threadIdx.x >> 6;
#pragma unroll
  for (int i = 0; i < 16; ++i) {
    int r = rg * 16 + i;
    tile[r][c] = in[(size_t)(k0 + r) * N + n0 + c];
  }
  __syncthreads();
#pragma unroll
  for (int i = 0; i < 16; ++i) {
    int nl = rg * 16 + i;
    out[(size_t)(n0 + nl) * K + k0 + c] = f2bf(tile[c][nl]);
  }
}

// Wq/Wk/Wv: [H][1024][64] f32 -> rows (zoff + h*64 + d) of [3072][1024] bf16
__global__ __launch_bounds__(256) void transpose_head(const float* __restrict__ W,
                                                      u16* __restrict__ out, int zoff) {
  __shared__ float tile[64][65];
  const int k0 = blockIdx.x * 64, h = blockIdx.y;
  const float* in = W + (size_t)h * 1024 * 64;
  const int c = threadIdx.x & 63, rg = threadIdx.x >> 6;
#pragma unroll
  for (int i = 0; i < 16; ++i) {
    int r = rg * 16 + i;
    tile[r][c] = in[(size_t)(k0 + r) * 64 + c];
  }
  __syncthreads();
#pragma unroll
  for (int i = 0; i < 16; ++i) {
    int nl = rg * 16 + i;
    out[(size_t)(zoff + h * 64 + nl) * 1024 + k0 + c] = f2bf(tile[c][nl]);
  }
}

// ---------------- LayerNorm over sequence axis T (per (b,c)) ---------------
__global__ __launch_bounds__(256) void ln_partial(const float* __restrict__ x,
                                                  float2* __restrict__ part) {
  const int b = blockIdx.x >> 4, c0 = (blockIdx.x & 15) * 64;
  const int c = c0 + (threadIdx.x & 63), tg = threadIdx.x >> 6;
  const int t0 = blockIdx.y * 256 + tg * 64;
  float s = 0.f, sq = 0.f;
  const float* p = x + (size_t)(b * 2048 + t0) * 1024 + c;
#pragma unroll 8
  for (int i = 0; i < 64; ++i) {
    float v = p[(size_t)i * 1024];
    s += v; sq += v * v;
  }
  __shared__ float ss[256], sb[256];
  ss[threadIdx.x] = s; sb[threadIdx.x] = sq;
  __syncthreads();
  if (threadIdx.x < 64) {
    s  = ss[threadIdx.x] + ss[threadIdx.x + 64] + ss[threadIdx.x + 128] + ss[threadIdx.x + 192];
    sq = sb[threadIdx.x] + sb[threadIdx.x + 64] + sb[threadIdx.x + 128] + sb[threadIdx.x + 192];
    part[(size_t)(b * 1024 + c) * 8 + blockIdx.y] = make_float2(s, sq);
  }
}

__global__ __launch_bounds__(256) void ln_stats(const float2* __restrict__ part,
                                                float2* __restrict__ stats) {
  const int bc = blockIdx.x * 256 + threadIdx.x;
  float s = 0.f, sq = 0.f;
#pragma unroll
  for (int i = 0; i < 8; ++i) {
    float2 v = part[(size_t)bc * 8 + i];
    s += v.x; sq += v.y;
  }
  const float mean = s * (1.0f / 2048.0f);
  const float var = (sq - 2048.0f * mean * mean) * (1.0f / 2047.0f);  // ddof=1
  stats[bc] = make_float2(mean, rsqrtf(var + 1e-5f));
}

__global__ __launch_bounds__(256) void ln_apply(const float* __restrict__ x,
                                                const float2* __restrict__ stats,
                                                const float* __restrict__ g,
                                                const float* __restrict__ be,
                                                u16* __restrict__ out) {
  const size_t flat = ((size_t)blockIdx.x * 256 + threadIdx.x) * 4;
  const int b = (int)(flat >> 21);
  const int c = (int)(flat & 1023);
  float4 xv = *reinterpret_cast<const float4*>(x + flat);
  float vs[4] = {xv.x, xv.y, xv.z, xv.w};
  u16x4 o;
#pragma unroll
  for (int j = 0; j < 4; ++j) {
    float2 st = stats[b * 1024 + c + j];
    o[j] = f2bf(g[c + j] * (vs[j] - st.x) * st.y + be[c + j]);
  }
  *reinterpret_cast<u16x4*>(out + flat) = o;
}

// ---------------- GEMM: C = A[M,K] x Bt[N,K]^T -----------------------------
// Double-buffered 2-phase: STAGE(t+1) issued before compute(t); one barrier
// (vmcnt(0)+lgkmcnt(0) drain) per K-step. XCD-aware block swizzle.
// EPI 0: store bf16.  1: +bias, ReLU, bf16.  2: +bias +resid, f32.
template <int MI, int NI, int EPI>
__global__ __launch_bounds__(256) void gemm_kernel(const u16* __restrict__ A,
                                                   const u16* __restrict__ Bt,
                                                   u16* __restrict__ outb,
                                                   float* __restrict__ outf,
                                                   const float* __restrict__ bias,
                                                   const float* __restrict__ resid,
                                                   int N, int K) {
  constexpr int BM = MI * 32, BN = NI * 32;   // 2x2 waves per block
  __shared__ alignas(16) u16 sA[2][BM * 32];
  __shared__ alignas(16) u16 sB[2][BN * 32];
  // T1: XCD swizzle (valid: all grids have nwg % 8 == 0)
  const int gx = gridDim.x;
  const int nwg = gx * gridDim.y;
  int bid = blockIdx.y * gx + blockIdx.x;
  bid = (bid & 7) * (nwg >> 3) + (bid >> 3);
  const int n0 = (bid % gx) * BN, m0 = (bid / gx) * BM;
  const int tid = threadIdx.x, lane = tid & 63, wid = tid >> 6;
  const int wm = (wid >> 1) * (MI * 16), wn = (wid & 1) * (NI * 16);
  const int lr = lane & 15, lg = lane >> 4;
  constexpr int CA = BM / 64;
  constexpr int CB = BN / 64;
  f32x4 acc[MI][NI] = {};

  auto stage = [&](int buf, int k0) {
#pragma unroll
    for (int i = 0; i < CA; ++i) {
      const int c = wid * CA + i, g = c * 64 + lane;
      gll16(A + (size_t)(m0 + (g >> 2)) * K + k0 + (g & 3) * 8, &sA[buf][c * 512]);
    }
#pragma unroll
    for (int i = 0; i < CB; ++i) {
      const int c = wid * CB + i, g = c * 64 + lane;
      gll16(Bt + (size_t)(n0 + (g >> 2)) * K + k0 + (g & 3) * 8, &sB[buf][c * 512]);
    }
  };

  const int nsteps = K >> 5;
  stage(0, 0);
  __syncthreads();  // drains vmcnt(0): first tile ready
  int cur = 0;
  for (int t = 0; t < nsteps; ++t) {
    if (t + 1 < nsteps) stage(cur ^ 1, (t + 1) * 32);  // prefetch flies under MFMA
    bf16x8 af[MI], bfr[NI];
#pragma unroll
    for (int mi = 0; mi < MI; ++mi) af[mi] = ldbf8(&sA[cur][(wm + mi * 16 + lr) * 32 + lg * 8]);
#pragma unroll
    for (int ni = 0; ni < NI; ++ni) bfr[ni] = ldbf8(&sB[cur][(wn + ni * 16 + lr) * 32 + lg * 8]);
    __builtin_amdgcn_s_setprio(1);
#pragma unroll
    for (int mi = 0; mi < MI; ++mi)
#pragma unroll
      for (int ni = 0; ni < NI; ++ni)
        acc[mi][ni] = MFMA16(af[mi], bfr[ni], acc[mi][ni], 0, 0, 0);
    __builtin_amdgcn_s_setprio(0);
    __syncthreads();  // drain next-tile loads (vmcnt 0) + WAR before overwrite
    cur ^= 1;
  }

#pragma unroll
  for (int mi = 0; mi < MI; ++mi)
#pragma unroll
    for (int ni = 0; ni < NI; ++ni)
#pragma unroll
      for (int r = 0; r < 4; ++r) {
        const int row = m0 + wm + mi * 16 + lg * 4 + r;   // C/D: row=(lane>>4)*4+reg
        const int col = n0 + wn + ni * 16 + lr;           //      col=lane&15
        float v = acc[mi][ni][r];
        if (EPI == 0) {
          outb[(size_t)row * N + col] = f2bf(v);
        } else if (EPI == 1) {
          v += bias[col];
          v = fmaxf(v, 0.f);
          outb[(size_t)row * N + col] = f2bf(v);
        } else {
          v += bias[col] + resid[(size_t)row * N + col];
          outf[(size_t)row * N + col] = v;
        }
      }
}

// ---------------- causal flash attention: split-s partial pass -------------
// qk: bf16 [4096 tok][2048] (Q|K per head).  vt: bf16 [1024 hd][4096 tok].
__global__ __launch_bounds__(256) void attn_partial(const u16* __restrict__ qk,
                                                    const u16* __restrict__ vt,
                                                    u16* __restrict__ Opart,
                                                    float2* __restrict__ ml) {
  const int xr = 79 - (int)blockIdx.x;  // heavy (long-range) blocks first
  int qb, ch, nc;
  if (xr < 8)       { qb = xr;                ch = 0;            nc = 1; }
  else if (xr < 24) { qb = 8 + ((xr - 8) >> 1);  ch = (xr - 8) & 1;  nc = 2; }
  else if (xr < 48) { qb = 16 + (xr - 24) / 3;   ch = (xr - 24) % 3; nc = 3; }
  else              { qb = 24 + ((xr - 48) >> 2); ch = (xr - 48) & 3; nc = 4; }
  const int nt_tot = qb + 1;
  const int t0 = (ch * nt_tot) / nc;
  const int t1 = ((ch + 1) * nt_tot) / nc;
  const int bh = blockIdx.y, b = bh >> 4, h = bh & 15;
  const int slot = bh * 80 + xr;
  const int q0 = qb * 64;
  const int tid = threadIdx.x, lane = tid & 63, w = tid >> 6;
  const int lr = lane & 15, lg = lane >> 4;
  __shared__ alignas(16) u16 sK[2][64 * 64];   // [s][d], 16B-granule XOR swizzle
  __shared__ alignas(16) u16 sV[2][64 * 64];   // [d][s], same swizzle
  __shared__ alignas(16) u16 sP[4][16 * 64];   // per-wave P, XOR-swizzled

  const size_t qrow = (size_t)(b * 2048 + q0 + w * 16 + lr) * 2048 + h * 64;
  const bf16x8 aq0 = ldbf8(qk + qrow + lg * 8);
  const bf16x8 aq1 = ldbf8(qk + qrow + 32 + lg * 8);

  float m_i[4], l_i[4];
  f32x4 acc[4];
#pragma unroll
  for (int r = 0; r < 4; ++r) { m_i[r] = -1e30f; l_i[r] = 0.f; }
#pragma unroll
  for (int dn = 0; dn < 4; ++dn) acc[dn] = f32x4{0.f, 0.f, 0.f, 0.f};

  auto stage = [&](int buf, int s0) {
#pragma unroll
    for (int i = 0; i < 2; ++i) {
      const int c = w * 2 + i;
      const int g = c * 64 + lane;
      const int row = g >> 3;
      const int cs = (g & 7) ^ (row & 7);
      gll16(qk + (size_t)(b * 2048 + s0 + row) * 2048 + 1024 + h * 64 + cs * 8,
            &sK[buf][c * 512]);
      gll16(vt + (size_t)(h * 64 + row) * 4096 + b * 2048 + s0 + cs * 8,
            &sV[buf][c * 512]);
    }
  };

  stage(0, t0 * 64);
  constexpr float SC = 0.03125f * 1.44269504088896341f;  // C^-0.5 * log2(e)

  for (int t = t0; t < t1; ++t) {
    const int buf = (t - t0) & 1;
    if (t + 1 < t1) {
      stage(buf ^ 1, (t + 1) * 64);
      asm volatile("s_waitcnt vmcnt(4)" ::: "memory");
    } else {
      asm volatile("s_waitcnt vmcnt(0)" ::: "memory");
    }
    __builtin_amdgcn_s_barrier();
    asm volatile("" ::: "memory");

    const u16* Kb = sK[buf];
    const u16* Vb = sV[buf];
    f32x4 sf[4];
    __builtin_amdgcn_s_setprio(1);
#pragma unroll
    for (int sn = 0; sn < 4; ++sn) {  // S[16q x 64s] = Q . K^T
      const int row = sn * 16 + lr;
      const int x7 = lr & 7;
      bf16x8 k0f = ldbf8(&Kb[row * 64 + ((lg ^ x7) * 8)]);
      bf16x8 k1f = ldbf8(&Kb[row * 64 + (((4 + lg) ^ x7) * 8)]);
      f32x4 z = {0.f, 0.f, 0.f, 0.f};
      z = MFMA16(aq0, k0f, z, 0, 0, 0);
      z = MFMA16(aq1, k1f, z, 0, 0, 0);
      sf[sn] = z;
    }
    __builtin_amdgcn_s_setprio(0);

    const bool maskt = (t == nt_tot - 1);
    const int x7p = lr & 7;
    // scale + causal mask in place
#pragma unroll
    for (int sn = 0; sn < 4; ++sn)
#pragma unroll
      for (int r = 0; r < 4; ++r) {
        float v = sf[sn][r] * SC;
        if (maskt) {
          const int ql = w * 16 + lg * 4 + r;
          if (sn * 16 + lr > ql) v = -1e30f;
        }
        sf[sn][r] = v;
      }
    // row maxima
    float mrow[4];
#pragma unroll
    for (int r = 0; r < 4; ++r) {
      float mx = fmaxf(fmaxf(sf[0][r], sf[1][r]), fmaxf(sf[2][r], sf[3][r]));
      mx = fmaxf(mx, __shfl_xor(mx, 1, 16));
      mx = fmaxf(mx, __shfl_xor(mx, 2, 16));
      mx = fmaxf(mx, __shfl_xor(mx, 4, 16));
      mx = fmaxf(mx, __shfl_xor(mx, 8, 16));
      mrow[r] = mx;
    }
    // T13 defer-max: skip rescale while growth <= 8 (exp2 domain)
    const bool small = (mrow[0] <= m_i[0] + 8.f) && (mrow[1] <= m_i[1] + 8.f) &&
                       (mrow[2] <= m_i[2] + 8.f) && (mrow[3] <= m_i[3] + 8.f);
    if (!__all(small)) {
#pragma unroll
      for (int r = 0; r < 4; ++r) {
        const float mnew = fmaxf(m_i[r], mrow[r]);
        const float al = exp2f(m_i[r] - mnew);
        l_i[r] *= al;
        acc[0][r] *= al; acc[1][r] *= al; acc[2][r] *= al; acc[3][r] *= al;
        m_i[r] = mnew;
      }
    }
    // P = exp2(S - m), row sums, swizzled P store
#pragma unroll
    for (int r = 0; r < 4; ++r) {
      const float p0 = exp2f(sf[0][r] - m_i[r]), p1 = exp2f(sf[1][r] - m_i[r]);
      const float p2 = exp2f(sf[2][r] - m_i[r]), p3 = exp2f(sf[3][r] - m_i[r]);
      float rs = (p0 + p1) + (p2 + p3);
      rs += __shfl_xor(rs, 1, 16);
      rs += __shfl_xor(rs, 2, 16);
      rs += __shfl_xor(rs, 4, 16);
      rs += __shfl_xor(rs, 8, 16);
      l_i[r] += rs;
      const int prow = lg * 4 + r;
      const int pb = prow * 64, px = prow & 7;
      sP[w][pb + (((lr >> 3) ^ px) * 8) + (lr & 7)]       = f2bf(p0);
      sP[w][pb + (((2 + (lr >> 3)) ^ px) * 8) + (lr & 7)] = f2bf(p1);
      sP[w][pb + (((4 + (lr >> 3)) ^ px) * 8) + (lr & 7)] = f2bf(p2);
      sP[w][pb + (((6 + (lr >> 3)) ^ px) * 8) + (lr & 7)] = f2bf(p3);
    }

    // O += P . V   (wave-local P; compiler inserts lgkmcnt for the RAW)
    const bf16x8 pa0 = ldbf8(&sP[w][lr * 64 + ((lg ^ x7p) * 8)]);
    const bf16x8 pa1 = ldbf8(&sP[w][lr * 64 + (((4 + lg) ^ x7p) * 8)]);
    __builtin_amdgcn_s_setprio(1);
#pragma unroll
    for (int dn = 0; dn < 4; ++dn) {
      const int row = dn * 16 + lr;
      bf16x8 v0f = ldbf8(&Vb[row * 64 + ((lg ^ x7p) * 8)]);
      bf16x8 v1f = ldbf8(&Vb[row * 64 + (((4 + lg) ^ x7p) * 8)]);
      acc[dn] = MFMA16(pa0, v0f, acc[dn], 0, 0, 0);
      acc[dn] = MFMA16(pa1, v1f, acc[dn], 0, 0, 0);
    }
    __builtin_amdgcn_s_setprio(0);
    asm volatile("" ::: "memory");
    __builtin_amdgcn_s_barrier();  // WAR guard before next stage overwrites
    asm volatile("" ::: "memory");
  }

  // partial epilogue: unnormalized O (bf16) + (m,l) per row
  const int rbase = w * 16 + lg * 4;
#pragma unroll
  for (int r = 0; r < 4; ++r) {
    const int row = rbase + r;
    if (lr == 0) ml[(size_t)slot * 64 + row] = make_float2(m_i[r], l_i[r]);
#pragma unroll
    for (int dn = 0; dn < 4; ++dn)
      Opart[((size_t)slot * 64 + row) * 64 + dn * 16 + lr] = f2bf(acc[dn][r]);
  }
}

// ---------------- attention merge + residual -------------------------------
__global__ __launch_bounds__(256) void attn_merge(const u16* __restrict__ Opart,
                                                  const float2* __restrict__ ml,
                                                  const float* __restrict__ x,
                                                  float* __restrict__ x2) {
  const int qb = blockIdx.x, bh = blockIdx.y, b = bh >> 4, h = bh & 15;
  int nc, s0;
  if (qb < 8)       { nc = 1; s0 = qb; }
  else if (qb < 16) { nc = 2; s0 = 8 + (qb - 8) * 2; }
  else if (qb < 24) { nc = 3; s0 = 24 + (qb - 16) * 3; }
  else              { nc = 4; s0 = 48 + (qb - 24) * 4; }
  const size_t slot0 = (size_t)bh * 80 + s0;
  const int tid = threadIdx.x;
  const int row = tid >> 2, d0 = (tid & 3) * 16;

  float wgt[4];
  float mmax = -1e30f, lsum = 0.f;
  for (int i = 0; i < nc; ++i) {
    float2 v = ml[(slot0 + i) * 64 + row];
    wgt[i] = v.x;
    mmax = fmaxf(mmax, v.x);
  }
  for (int i = 0; i < nc; ++i) {
    float2 v = ml[(slot0 + i) * 64 + row];
    wgt[i] = exp2f(wgt[i] - mmax);
    lsum += wgt[i] * v.y;
  }
  const float inv = 1.0f / lsum;

#pragma unroll
  for (int half = 0; half < 2; ++half) {
    const int d = d0 + half * 8;
    float o[8] = {0.f, 0.f, 0.f, 0.f, 0.f, 0.f, 0.f, 0.f};
    for (int i = 0; i < nc; ++i) {
      u16x8 v = *reinterpret_cast<const u16x8*>(&Opart[((slot0 + i) * 64 + row) * 64 + d]);
#pragma unroll
      for (int j = 0; j < 8; ++j) o[j] += wgt[i] * bf2f(v[j]);
    }
    const size_t idx = ((size_t)(b * 2048 + qb * 64 + row)) * 1024 + h * 64 + d;
    float4 x0 = *reinterpret_cast<const float4*>(x + idx);
    float4 x1 = *reinterpret_cast<const float4*>(x + idx + 4);
    float4 o0 = make_float4(x0.x + o[0] * inv, x0.y + o[1] * inv, x0.z + o[2] * inv, x0.w + o[3] * inv);
    float4 o1 = make_float4(x1.x + o[4] * inv, x1.y + o[5] * inv, x1.z + o[6] * inv, x1.w + o[7] * inv);
    *reinterpret_cast<float4*>(x2 + idx) = o0;
    *reinterpret_cast<float4*>(x2 + idx + 4) = o1;
  }
}

// ---------------------------------------------------------------------------
extern "C" void kernel_launch(void* const* d_in, const int* in_sizes, int n_in,
                              void* d_out, int out_size, void* d_ws, size_t ws_size,
                              hipStream_t stream) {
  const float* x   = (const float*)d_in[0];
  const float* Wq  = (const float*)d_in[1];
  const float* Wk  = (const float*)d_in[2];
  const float* Wv  = (const float*)d_in[3];
  const float* W1  = (const float*)d_in[4];
  const float* b1  = (const float*)d_in[5];
  const float* W2  = (const float*)d_in[6];
  const float* b2  = (const float*)d_in[7];
  const float* g1  = (const float*)d_in[8];
  const float* be1 = (const float*)d_in[9];
  const float* g2  = (const float*)d_in[10];
  const float* be2 = (const float*)d_in[11];
  float* out = (float*)d_out;

  char* ws = (char*)d_ws;
  size_t off = 0;
  auto alloc = [&](size_t bytes) { char* p = ws + off; off += (bytes + 255) & ~(size_t)255; return p; };
  u16*    qkb   = (u16*)alloc(4096ull * 2048 * 2);   // [tok][Q|K]          16MB
  u16*    vtb   = (u16*)alloc(1024ull * 4096 * 2);   // [hd][tok]            8MB
  (void)alloc(4096ull * 1024 * 2);                   // h1 overflow region   8MB
  u16*    h1    = qkb;                               // MLP1 out aliases qk+vt+overflow (32MB)
  float*  x2    = (float*)alloc(4096ull * 1024 * 4); // x + attn            16MB
  u16*    hbuf  = (u16*)alloc(4096ull * 1024 * 2);   // LN outputs           8MB
  u16*    wqkvt = (u16*)alloc(3072ull * 1024 * 2);
  u16*    w1t   = (u16*)alloc(4096ull * 1024 * 2);
  u16*    w2t   = (u16*)alloc(1024ull * 4096 * 2);
  float2* part  = (float2*)alloc(2048ull * 8 * 8);
  float2* stats = (float2*)alloc(2048ull * 8);
  u16*    Opart = (u16*)alloc(32ull * 80 * 64 * 64 * 2);   // ~21MB
  float2* ml    = (float2*)alloc(32ull * 80 * 64 * 8);     // ~1.3MB
  (void)ws_size; (void)in_sizes; (void)n_in; (void)out_size;

  // weight prep (bf16, B-transposed)
  transpose_head<<<dim3(16, 16), 256, 0, stream>>>(Wq, wqkvt, 0);
  transpose_head<<<dim3(16, 16), 256, 0, stream>>>(Wk, wqkvt, 1024);
  transpose_head<<<dim3(16, 16), 256, 0, stream>>>(Wv, wqkvt, 2048);
  transpose_big<<<dim3(16, 64), 256, 0, stream>>>(W1, w1t, 1024, 4096);
  transpose_big<<<dim3(64, 16), 256, 0, stream>>>(W2, w2t, 4096, 1024);

  // LN1 (over T) -> hbuf
  ln_partial<<<dim3(32, 8), 256, 0, stream>>>(x, part);
  ln_stats<<<8, 256, 0, stream>>>(part, stats);
  ln_apply<<<4096, 256, 0, stream>>>(x, stats, g1, be1, hbuf);

  // QK GEMM: [4096,1024] x W_qk^T -> qkb [4096][2048]
  gemm_kernel<4, 4, 0><<<dim3(16, 32), 256, 0, stream>>>(hbuf, wqkvt, qkb, nullptr, nullptr, nullptr, 2048, 1024);
  // V^T GEMM: Wv^T [1024,1024] x LN1^T -> vtb [1024][4096]
  gemm_kernel<4, 4, 0><<<dim3(32, 8), 256, 0, stream>>>(wqkvt + 2048 * 1024, hbuf, vtb, nullptr, nullptr, nullptr, 4096, 1024);

  // attention: split-s partials, then merge + residual -> x2 (f32)
  attn_partial<<<dim3(80, 32), 256, 0, stream>>>(qkb, vtb, Opart, ml);
  attn_merge<<<dim3(32, 32), 256, 0, stream>>>(Opart, ml, x, x2);

  // LN2 (over T) -> hbuf
  ln_partial<<<dim3(32, 8), 256, 0, stream>>>(x2, part);
  ln_stats<<<8, 256, 0, stream>>>(part, stats);
  ln_apply<<<4096, 256, 0, stream>>>(x2, stats, g2, be2, hbuf);

  // MLP1: relu(h @ W1 + b1) -> h1 (bf16 [4096][4096])
  gemm_kernel<4, 4, 1><<<dim3(32, 32), 256, 0, stream>>>(hbuf, w1t, h1, nullptr, b1, nullptr, 4096, 1024);

  // MLP2: x2 + h1 @ W2 + b2 -> out (f32)
  gemm_kernel<4, 2, 2><<<dim3(16, 32), 256, 0, stream>>>(h1, w2t, nullptr, out, b2, x2, 1024, 4096);
}

// Round 5
// 292.453 us; speedup vs baseline: 1.5562x; 1.0558x over previous
//
#include <hip/hip_runtime.h>

// ---------------------------------------------------------------------------
// Transformer block on MI355X (gfx950), bf16 MFMA pipeline, fp32 residual/LN.
//   x:[2,2048,1024]  LN over T (ddof=1) -> QK GEMM + V^T GEMM -> causal flash
//   attn (split-s flash-decoding, dbuf LDS, swizzled global_load_lds) + merge
//   -> +resid -> LN -> MLP -> +resid
// GEMMs: dbuf 2-phase with COUNTED vmcnt (loads span barriers) + XCD swizzle.
// Attn: softmax scale folded into Wq; defer-max fast path; deferred l-reduce.
// ---------------------------------------------------------------------------

typedef __bf16 bf16x8 __attribute__((ext_vector_type(8)));
typedef float f32x4 __attribute__((ext_vector_type(4)));
typedef unsigned short u16;
typedef u16 u16x8 __attribute__((ext_vector_type(8)));
typedef u16 u16x4 __attribute__((ext_vector_type(4)));

#define MFMA16 __builtin_amdgcn_mfma_f32_16x16x32_bf16

__device__ __forceinline__ u16 f2bf(float f) {  // native v_cvt (RNE)
  return __builtin_bit_cast(u16, (__bf16)f);
}
__device__ __forceinline__ float bf2f(u16 u) {
  return __builtin_bit_cast(float, (unsigned)u << 16);
}
__device__ __forceinline__ bf16x8 ldbf8(const u16* p) {
  return __builtin_bit_cast(bf16x8, *reinterpret_cast<const u16x8*>(p));
}
// async global->LDS, 16B per lane, dest = wave-uniform base + lane*16
__device__ __forceinline__ void gll16(const void* g, void* l) {
  __builtin_amdgcn_global_load_lds((const __attribute__((address_space(1))) void*)g,
                                   (__attribute__((address_space(3))) void*)l, 16, 0, 0);
}
template <int N>
__device__ __forceinline__ void wait_vm() {
  if constexpr (N == 0)      asm volatile("s_waitcnt vmcnt(0)" ::: "memory");
  else if constexpr (N == 2) asm volatile("s_waitcnt vmcnt(2)" ::: "memory");
  else if constexpr (N == 3) asm volatile("s_waitcnt vmcnt(3)" ::: "memory");
  else if constexpr (N == 4) asm volatile("s_waitcnt vmcnt(4)" ::: "memory");
  else if constexpr (N == 6) asm volatile("s_waitcnt vmcnt(6)" ::: "memory");
  else                       asm volatile("s_waitcnt vmcnt(8)" ::: "memory");
}
__device__ __forceinline__ void barrier_raw() {
  asm volatile("" ::: "memory");
  __builtin_amdgcn_s_barrier();
  asm volatile("" ::: "memory");
}

// ---------------- weight transpose (f32 [K][N] -> bf16 [N][K]) -------------
__global__ __launch_bounds__(256) void transpose_big(const float* __restrict__ in,
                                                     u16* __restrict__ out, int K, int N) {
  __shared__ float tile[64][65];
  const int k0 = blockIdx.x * 64, n0 = blockIdx.y * 64;
  const int c = threadIdx.x & 63, rg = threadIdx.x >> 6;
#pragma unroll
  for (int i = 0; i < 16; ++i) {
    int r = rg * 16 + i;
    tile[r][c] = in[(size_t)(k0 + r) * N + n0 + c];
  }
  __syncthreads();
#pragma unroll
  for (int i = 0; i < 16; ++i) {
    int nl = rg * 16 + i;
    out[(size_t)(n0 + nl) * K + k0 + c] = f2bf(tile[c][nl]);
  }
}

// Wq/Wk/Wv: [H][1024][64] f32 -> rows (zoff + h*64 + d) of [3072][1024] bf16.
// scale folds softmax scaling into Wq (Q pre-scaled by C^-0.5 * log2 e).
__global__ __launch_bounds__(256) void transpose_head(const float* __restrict__ W,
                                                      u16* __restrict__ out, int zoff,
                                                      float scale) {
  __shared__ float tile[64][65];
  const int k0 = blockIdx.x * 64, h = blockIdx.y;
  const float* in = W + (size_t)h * 1024 * 64;
  const int c = threadIdx.x & 63, rg = threadIdx.x >> 6;
#pragma unroll
  for (int i = 0; i < 16; ++i) {
    int r = rg * 16 + i;
    tile[r][c] = in[(size_t)(k0 + r) * 64 + c];
  }
  __syncthreads();
#pragma unroll
  for (int i = 0; i < 16; ++i) {
    int nl = rg * 16 + i;
    out[(size_t)(zoff + h * 64 + nl) * 1024 + k0 + c] = f2bf(tile[c][nl] * scale);
  }
}

// ---------------- LayerNorm over sequence axis T (per (b,c)) ---------------
__global__ __launch_bounds__(256) void ln_partial(const float* __restrict__ x,
                                                  float2* __restrict__ part) {
  const int b = blockIdx.x >> 4, c0 = (blockIdx.x & 15) * 64;
  const int c = c0 + (threadIdx.x & 63), tg = threadIdx.x >> 6;
  const int t0 = blockIdx.y * 256 + tg * 64;
  float s = 0.f, sq = 0.f;
  const float* p = x + (size_t)(b * 2048 + t0) * 1024 + c;
#pragma unroll 8
  for (int i = 0; i < 64; ++i) {
    float v = p[(size_t)i * 1024];
    s += v; sq += v * v;
  }
  __shared__ float ss[256], sb[256];
  ss[threadIdx.x] = s; sb[threadIdx.x] = sq;
  __syncthreads();
  if (threadIdx.x < 64) {
    s  = ss[threadIdx.x] + ss[threadIdx.x + 64] + ss[threadIdx.x + 128] + ss[threadIdx.x + 192];
    sq = sb[threadIdx.x] + sb[threadIdx.x + 64] + sb[threadIdx.x + 128] + sb[threadIdx.x + 192];
    part[(size_t)(b * 1024 + c) * 8 + blockIdx.y] = make_float2(s, sq);
  }
}

__global__ __launch_bounds__(256) void ln_stats(const float2* __restrict__ part,
                                                float2* __restrict__ stats) {
  const int bc = blockIdx.x * 256 + threadIdx.x;
  float s = 0.f, sq = 0.f;
#pragma unroll
  for (int i = 0; i < 8; ++i) {
    float2 v = part[(size_t)bc * 8 + i];
    s += v.x; sq += v.y;
  }
  const float mean = s * (1.0f / 2048.0f);
  const float var = (sq - 2048.0f * mean * mean) * (1.0f / 2047.0f);  // ddof=1
  stats[bc] = make_float2(mean, rsqrtf(var + 1e-5f));
}

__global__ __launch_bounds__(256) void ln_apply(const float* __restrict__ x,
                                                const float2* __restrict__ stats,
                                                const float* __restrict__ g,
                                                const float* __restrict__ be,
                                                u16* __restrict__ out) {
  const size_t flat = ((size_t)blockIdx.x * 256 + threadIdx.x) * 4;
  const int b = (int)(flat >> 21);
  const int c = (int)(flat & 1023);
  float4 xv = *reinterpret_cast<const float4*>(x + flat);
  float vs[4] = {xv.x, xv.y, xv.z, xv.w};
  u16x4 o;
#pragma unroll
  for (int j = 0; j < 4; ++j) {
    float2 st = stats[b * 1024 + c + j];
    o[j] = f2bf(g[c + j] * (vs[j] - st.x) * st.y + be[c + j]);
  }
  *reinterpret_cast<u16x4*>(out + flat) = o;
}

// ---------------- GEMM: C = A[M,K] x Bt[N,K]^T -----------------------------
// dbuf 2-phase, counted vmcnt: stage(t+1) stays in flight across the compute
// barriers; only tile t's loads are waited (vmcnt(LOADS)). Raw s_barriers.
// EPI 0: store bf16.  1: +bias, ReLU, bf16.  2: +bias +resid, f32.
template <int MI, int NI, int EPI>
__global__ __launch_bounds__(256) void gemm_kernel(const u16* __restrict__ A,
                                                   const u16* __restrict__ Bt,
                                                   u16* __restrict__ outb,
                                                   float* __restrict__ outf,
                                                   const float* __restrict__ bias,
                                                   const float* __restrict__ resid,
                                                   int N, int K) {
  constexpr int BM = MI * 32, BN = NI * 32;   // 2x2 waves per block
  __shared__ alignas(16) u16 sA[2][BM * 32];
  __shared__ alignas(16) u16 sB[2][BN * 32];
  // T1: XCD swizzle (valid: all grids have nwg % 8 == 0)
  const int gx = gridDim.x;
  const int nwg = gx * gridDim.y;
  int bid = blockIdx.y * gx + blockIdx.x;
  bid = (bid & 7) * (nwg >> 3) + (bid >> 3);
  const int n0 = (bid % gx) * BN, m0 = (bid / gx) * BM;
  const int tid = threadIdx.x, lane = tid & 63, wid = tid >> 6;
  const int wm = (wid >> 1) * (MI * 16), wn = (wid & 1) * (NI * 16);
  const int lr = lane & 15, lg = lane >> 4;
  constexpr int CA = BM / 64;
  constexpr int CB = BN / 64;
  constexpr int LOADS = CA + CB;   // gll16 per wave per stage
  f32x4 acc[MI][NI] = {};

  auto stage = [&](int buf, int k0) {
#pragma unroll
    for (int i = 0; i < CA; ++i) {
      const int c = wid * CA + i, g = c * 64 + lane;
      gll16(A + (size_t)(m0 + (g >> 2)) * K + k0 + (g & 3) * 8, &sA[buf][c * 512]);
    }
#pragma unroll
    for (int i = 0; i < CB; ++i) {
      const int c = wid * CB + i, g = c * 64 + lane;
      gll16(Bt + (size_t)(n0 + (g >> 2)) * K + k0 + (g & 3) * 8, &sB[buf][c * 512]);
    }
  };

  const int nsteps = K >> 5;
  stage(0, 0);
  int cur = 0;
  for (int t = 0; t < nsteps; ++t) {
    if (t + 1 < nsteps) {
      stage(cur ^ 1, (t + 1) * 32);  // prefetch stays in flight across barriers
      wait_vm<LOADS>();              // tile t landed (its LOADS are the oldest)
    } else {
      wait_vm<0>();
    }
    barrier_raw();                   // whole tile visible to all waves
    bf16x8 af[MI], bfr[NI];
#pragma unroll
    for (int mi = 0; mi < MI; ++mi) af[mi] = ldbf8(&sA[cur][(wm + mi * 16 + lr) * 32 + lg * 8]);
#pragma unroll
    for (int ni = 0; ni < NI; ++ni) bfr[ni] = ldbf8(&sB[cur][(wn + ni * 16 + lr) * 32 + lg * 8]);
#pragma unroll
    for (int mi = 0; mi < MI; ++mi)
#pragma unroll
      for (int ni = 0; ni < NI; ++ni)
        acc[mi][ni] = MFMA16(af[mi], bfr[ni], acc[mi][ni], 0, 0, 0);
    barrier_raw();                   // WAR: reads done before next stage overwrites
    cur ^= 1;
  }

#pragma unroll
  for (int mi = 0; mi < MI; ++mi)
#pragma unroll
    for (int ni = 0; ni < NI; ++ni)
#pragma unroll
      for (int r = 0; r < 4; ++r) {
        const int row = m0 + wm + mi * 16 + lg * 4 + r;   // C/D: row=(lane>>4)*4+reg
        const int col = n0 + wn + ni * 16 + lr;           //      col=lane&15
        float v = acc[mi][ni][r];
        if (EPI == 0) {
          outb[(size_t)row * N + col] = f2bf(v);
        } else if (EPI == 1) {
          v += bias[col];
          v = fmaxf(v, 0.f);
          outb[(size_t)row * N + col] = f2bf(v);
        } else {
          v += bias[col] + resid[(size_t)row * N + col];
          outf[(size_t)row * N + col] = v;
        }
      }
}

// ---------------- causal flash attention: split-s partial pass -------------
// qk: bf16 [4096 tok][2048] (Q|K per head), Q pre-scaled to exp2 domain.
// vt: bf16 [1024 hd][4096 tok].
__global__ __launch_bounds__(256) void attn_partial(const u16* __restrict__ qk,
                                                    const u16* __restrict__ vt,
                                                    u16* __restrict__ Opart,
                                                    float2* __restrict__ ml) {
  const int xr = 79 - (int)blockIdx.x;  // heavy (long-range) blocks first
  int qb, ch, nc;
  if (xr < 8)       { qb = xr;                ch = 0;            nc = 1; }
  else if (xr < 24) { qb = 8 + ((xr - 8) >> 1);  ch = (xr - 8) & 1;  nc = 2; }
  else if (xr < 48) { qb = 16 + (xr - 24) / 3;   ch = (xr - 24) % 3; nc = 3; }
  else              { qb = 24 + ((xr - 48) >> 2); ch = (xr - 48) & 3; nc = 4; }
  const int nt_tot = qb + 1;
  const int t0 = (ch * nt_tot) / nc;
  const int t1 = ((ch + 1) * nt_tot) / nc;
  const int bh = blockIdx.y, b = bh >> 4, h = bh & 15;
  const int slot = bh * 80 + xr;
  const int q0 = qb * 64;
  const int tid = threadIdx.x, lane = tid & 63, w = tid >> 6;
  const int lr = lane & 15, lg = lane >> 4;
  __shared__ alignas(16) u16 sK[2][64 * 64];   // [s][d], 16B-granule XOR swizzle
  __shared__ alignas(16) u16 sV[2][64 * 64];   // [d][s], same swizzle
  __shared__ alignas(16) u16 sP[4][16 * 64];   // per-wave P, XOR-swizzled

  const size_t qrow = (size_t)(b * 2048 + q0 + w * 16 + lr) * 2048 + h * 64;
  const bf16x8 aq0 = ldbf8(qk + qrow + lg * 8);
  const bf16x8 aq1 = ldbf8(qk + qrow + 32 + lg * 8);

  float m_i[4], l_i[4];   // l_i: PER-LANE partial sums (reduced in epilogue)
  f32x4 acc[4];
#pragma unroll
  for (int r = 0; r < 4; ++r) { m_i[r] = -1e30f; l_i[r] = 0.f; }
#pragma unroll
  for (int dn = 0; dn < 4; ++dn) acc[dn] = f32x4{0.f, 0.f, 0.f, 0.f};

  auto stage = [&](int buf, int s0) {
#pragma unroll
    for (int i = 0; i < 2; ++i) {
      const int c = w * 2 + i;
      const int g = c * 64 + lane;
      const int row = g >> 3;
      const int cs = (g & 7) ^ (row & 7);
      gll16(qk + (size_t)(b * 2048 + s0 + row) * 2048 + 1024 + h * 64 + cs * 8,
            &sK[buf][c * 512]);
      gll16(vt + (size_t)(h * 64 + row) * 4096 + b * 2048 + s0 + cs * 8,
            &sV[buf][c * 512]);
    }
  };

  stage(0, t0 * 64);

  for (int t = t0; t < t1; ++t) {
    const int buf = (t - t0) & 1;
    if (t + 1 < t1) {
      stage(buf ^ 1, (t + 1) * 64);
      wait_vm<4>();
    } else {
      wait_vm<0>();
    }
    barrier_raw();

    const u16* Kb = sK[buf];
    const u16* Vb = sV[buf];
    f32x4 sf[4];
    __builtin_amdgcn_s_setprio(1);
#pragma unroll
    for (int sn = 0; sn < 4; ++sn) {  // S[16q x 64s] = Q . K^T (exp2 domain)
      const int row = sn * 16 + lr;
      const int x7 = lr & 7;
      bf16x8 k0f = ldbf8(&Kb[row * 64 + ((lg ^ x7) * 8)]);
      bf16x8 k1f = ldbf8(&Kb[row * 64 + (((4 + lg) ^ x7) * 8)]);
      f32x4 z = {0.f, 0.f, 0.f, 0.f};
      z = MFMA16(aq0, k0f, z, 0, 0, 0);
      z = MFMA16(aq1, k1f, z, 0, 0, 0);
      sf[sn] = z;
    }
    __builtin_amdgcn_s_setprio(0);

    if (t == nt_tot - 1) {  // causal mask (last tile only)
      const int qlb = w * 16 + lg * 4;
#pragma unroll
      for (int sn = 0; sn < 4; ++sn)
#pragma unroll
        for (int r = 0; r < 4; ++r)
          if (sn * 16 + lr > qlb + r) sf[sn][r] = -1e30f;
    }

    // defer-max fast path: full reduce+rescale only when growth > 8
    float pm[4];
    bool need = false;
#pragma unroll
    for (int r = 0; r < 4; ++r) {
      pm[r] = fmaxf(fmaxf(sf[0][r], sf[1][r]), fmaxf(sf[2][r], sf[3][r]));
      need = need || (pm[r] > m_i[r] + 8.f);
    }
    if (__any(need)) {
#pragma unroll
      for (int r = 0; r < 4; ++r) {
        float mx = pm[r];
        mx = fmaxf(mx, __shfl_xor(mx, 1, 16));
        mx = fmaxf(mx, __shfl_xor(mx, 2, 16));
        mx = fmaxf(mx, __shfl_xor(mx, 4, 16));
        mx = fmaxf(mx, __shfl_xor(mx, 8, 16));
        const float mnew = fmaxf(m_i[r], mx);
        const float al = exp2f(m_i[r] - mnew);
        l_i[r] *= al;
        acc[0][r] *= al; acc[1][r] *= al; acc[2][r] *= al; acc[3][r] *= al;
        m_i[r] = mnew;
      }
    }

    // P = exp2(S - m); per-lane l accumulation; swizzled P store
    const int x7p = lr & 7;
#pragma unroll
    for (int r = 0; r < 4; ++r) {
      const float p0 = exp2f(sf[0][r] - m_i[r]), p1 = exp2f(sf[1][r] - m_i[r]);
      const float p2 = exp2f(sf[2][r] - m_i[r]), p3 = exp2f(sf[3][r] - m_i[r]);
      l_i[r] += (p0 + p1) + (p2 + p3);
      const int prow = lg * 4 + r;
      const int pb = prow * 64, px = prow & 7;
      sP[w][pb + (((lr >> 3) ^ px) * 8) + (lr & 7)]       = f2bf(p0);
      sP[w][pb + (((2 + (lr >> 3)) ^ px) * 8) + (lr & 7)] = f2bf(p1);
      sP[w][pb + (((4 + (lr >> 3)) ^ px) * 8) + (lr & 7)] = f2bf(p2);
      sP[w][pb + (((6 + (lr >> 3)) ^ px) * 8) + (lr & 7)] = f2bf(p3);
    }

    // O += P . V   (wave-local P; compiler inserts lgkmcnt for the RAW)
    const bf16x8 pa0 = ldbf8(&sP[w][lr * 64 + ((lg ^ x7p) * 8)]);
    const bf16x8 pa1 = ldbf8(&sP[w][lr * 64 + (((4 + lg) ^ x7p) * 8)]);
    __builtin_amdgcn_s_setprio(1);
#pragma unroll
    for (int dn = 0; dn < 4; ++dn) {
      const int row = dn * 16 + lr;
      bf16x8 v0f = ldbf8(&Vb[row * 64 + ((lg ^ x7p) * 8)]);
      bf16x8 v1f = ldbf8(&Vb[row * 64 + (((4 + lg) ^ x7p) * 8)]);
      acc[dn] = MFMA16(pa0, v0f, acc[dn], 0, 0, 0);
      acc[dn] = MFMA16(pa1, v1f, acc[dn], 0, 0, 0);
    }
    __builtin_amdgcn_s_setprio(0);
    barrier_raw();  // WAR guard before next stage overwrites
  }

  // partial epilogue: reduce per-lane l, write unnormalized O (bf16) + (m,l)
  const int rbase = w * 16 + lg * 4;
#pragma unroll
  for (int r = 0; r < 4; ++r) {
    float ls = l_i[r];
    ls += __shfl_xor(ls, 1, 16);
    ls += __shfl_xor(ls, 2, 16);
    ls += __shfl_xor(ls, 4, 16);
    ls += __shfl_xor(ls, 8, 16);
    const int row = rbase + r;
    if (lr == 0) ml[(size_t)slot * 64 + row] = make_float2(m_i[r], ls);
#pragma unroll
    for (int dn = 0; dn < 4; ++dn)
      Opart[((size_t)slot * 64 + row) * 64 + dn * 16 + lr] = f2bf(acc[dn][r]);
  }
}

// ---------------- attention merge + residual -------------------------------
__global__ __launch_bounds__(256) void attn_merge(const u16* __restrict__ Opart,
                                                  const float2* __restrict__ ml,
                                                  const float* __restrict__ x,
                                                  float* __restrict__ x2) {
  const int qb = blockIdx.x, bh = blockIdx.y, b = bh >> 4, h = bh & 15;
  int nc, s0;
  if (qb < 8)       { nc = 1; s0 = qb; }
  else if (qb < 16) { nc = 2; s0 = 8 + (qb - 8) * 2; }
  else if (qb < 24) { nc = 3; s0 = 24 + (qb - 16) * 3; }
  else              { nc = 4; s0 = 48 + (qb - 24) * 4; }
  const size_t slot0 = (size_t)bh * 80 + s0;
  const int tid = threadIdx.x;
  const int row = tid >> 2, d0 = (tid & 3) * 16;

  float wgt[4];
  float mmax = -1e30f, lsum = 0.f;
  for (int i = 0; i < nc; ++i) {
    float2 v = ml[(slot0 + i) * 64 + row];
    wgt[i] = v.x;
    mmax = fmaxf(mmax, v.x);
  }
  for (int i = 0; i < nc; ++i) {
    float2 v = ml[(slot0 + i) * 64 + row];
    wgt[i] = exp2f(wgt[i] - mmax);
    lsum += wgt[i] * v.y;
  }
  const float inv = 1.0f / lsum;

#pragma unroll
  for (int half = 0; half < 2; ++half) {
    const int d = d0 + half * 8;
    float o[8] = {0.f, 0.f, 0.f, 0.f, 0.f, 0.f, 0.f, 0.f};
    for (int i = 0; i < nc; ++i) {
      u16x8 v = *reinterpret_cast<const u16x8*>(&Opart[((slot0 + i) * 64 + row) * 64 + d]);
#pragma unroll
      for (int j = 0; j < 8; ++j) o[j] += wgt[i] * bf2f(v[j]);
    }
    const size_t idx = ((size_t)(b * 2048 + qb * 64 + row)) * 1024 + h * 64 + d;
    float4 x0 = *reinterpret_cast<const float4*>(x + idx);
    float4 x1 = *reinterpret_cast<const float4*>(x + idx + 4);
    float4 o0 = make_float4(x0.x + o[0] * inv, x0.y + o[1] * inv, x0.z + o[2] * inv, x0.w + o[3] * inv);
    float4 o1 = make_float4(x1.x + o[4] * inv, x1.y + o[5] * inv, x1.z + o[6] * inv, x1.w + o[7] * inv);
    *reinterpret_cast<float4*>(x2 + idx) = o0;
    *reinterpret_cast<float4*>(x2 + idx + 4) = o1;
  }
}

// ---------------------------------------------------------------------------
extern "C" void kernel_launch(void* const* d_in, const int* in_sizes, int n_in,
                              void* d_out, int out_size, void* d_ws, size_t ws_size,
                              hipStream_t stream) {
  const float* x   = (const float*)d_in[0];
  const float* Wq  = (const float*)d_in[1];
  const float* Wk  = (const float*)d_in[2];
  const float* Wv  = (const float*)d_in[3];
  const float* W1  = (const float*)d_in[4];
  const float* b1  = (const float*)d_in[5];
  const float* W2  = (const float*)d_in[6];
  const float* b2  = (const float*)d_in[7];
  const float* g1  = (const float*)d_in[8];
  const float* be1 = (const float*)d_in[9];
  const float* g2  = (const float*)d_in[10];
  const float* be2 = (const float*)d_in[11];
  float* out = (float*)d_out;

  char* ws = (char*)d_ws;
  size_t off = 0;
  auto alloc = [&](size_t bytes) { char* p = ws + off; off += (bytes + 255) & ~(size_t)255; return p; };
  u16*    qkb   = (u16*)alloc(4096ull * 2048 * 2);   // [tok][Q|K]          16MB
  u16*    vtb   = (u16*)alloc(1024ull * 4096 * 2);   // [hd][tok]            8MB
  (void)alloc(4096ull * 1024 * 2);                   // h1 overflow region   8MB
  u16*    h1    = qkb;                               // MLP1 out aliases qk+vt+overflow (32MB)
  float*  x2    = (float*)alloc(4096ull * 1024 * 4); // x + attn            16MB
  u16*    hbuf  = (u16*)alloc(4096ull * 1024 * 2);   // LN outputs           8MB
  u16*    wqkvt = (u16*)alloc(3072ull * 1024 * 2);
  u16*    w1t   = (u16*)alloc(4096ull * 1024 * 2);
  u16*    w2t   = (u16*)alloc(1024ull * 4096 * 2);
  float2* part  = (float2*)alloc(2048ull * 8 * 8);
  float2* stats = (float2*)alloc(2048ull * 8);
  u16*    Opart = (u16*)alloc(32ull * 80 * 64 * 64 * 2);   // ~21MB
  float2* ml    = (float2*)alloc(32ull * 80 * 64 * 8);     // ~1.3MB
  (void)ws_size; (void)in_sizes; (void)n_in; (void)out_size;

  // weight prep (bf16, B-transposed); softmax scale folded into Wq
  const float SC = 0.03125f * 1.44269504088896341f;  // C^-0.5 * log2(e)
  transpose_head<<<dim3(16, 16), 256, 0, stream>>>(Wq, wqkvt, 0, SC);
  transpose_head<<<dim3(16, 16), 256, 0, stream>>>(Wk, wqkvt, 1024, 1.0f);
  transpose_head<<<dim3(16, 16), 256, 0, stream>>>(Wv, wqkvt, 2048, 1.0f);
  transpose_big<<<dim3(16, 64), 256, 0, stream>>>(W1, w1t, 1024, 4096);
  transpose_big<<<dim3(64, 16), 256, 0, stream>>>(W2, w2t, 4096, 1024);

  // LN1 (over T) -> hbuf
  ln_partial<<<dim3(32, 8), 256, 0, stream>>>(x, part);
  ln_stats<<<8, 256, 0, stream>>>(part, stats);
  ln_apply<<<4096, 256, 0, stream>>>(x, stats, g1, be1, hbuf);

  // QK GEMM: [4096,1024] x W_qk^T -> qkb [4096][2048]
  gemm_kernel<4, 4, 0><<<dim3(16, 32), 256, 0, stream>>>(hbuf, wqkvt, qkb, nullptr, nullptr, nullptr, 2048, 1024);
  // V^T GEMM: Wv^T [1024,1024] x LN1^T -> vtb [1024][4096]
  gemm_kernel<4, 4, 0><<<dim3(32, 8), 256, 0, stream>>>(wqkvt + 2048 * 1024, hbuf, vtb, nullptr, nullptr, nullptr, 4096, 1024);

  // attention: split-s partials, then merge + residual -> x2 (f32)
  attn_partial<<<dim3(80, 32), 256, 0, stream>>>(qkb, vtb, Opart, ml);
  attn_merge<<<dim3(32, 32), 256, 0, stream>>>(Opart, ml, x, x2);

  // LN2 (over T) -> hbuf
  ln_partial<<<dim3(32, 8), 256, 0, stream>>>(x2, part);
  ln_stats<<<8, 256, 0, stream>>>(part, stats);
  ln_apply<<<4096, 256, 0, stream>>>(x2, stats, g2, be2, hbuf);

  // MLP1: relu(h @ W1 + b1) -> h1 (bf16 [4096][4096])
  gemm_kernel<4, 4, 1><<<dim3(32, 32), 256, 0, stream>>>(hbuf, w1t, h1, nullptr, b1, nullptr, 4096, 1024);

  // MLP2: x2 + h1 @ W2 + b2 -> out (f32)
  gemm_kernel<4, 2, 2><<<dim3(16, 32), 256, 0, stream>>>(h1, w2t, nullptr, out, b2, x2, 1024, 4096);
}

// Round 6
// 269.875 us; speedup vs baseline: 1.6864x; 1.0837x over previous
//
#include <hip/hip_runtime.h>

// ---------------------------------------------------------------------------
// Transformer block on MI355X (gfx950), bf16 MFMA pipeline, fp32 residual/LN.
//   x:[2,2048,1024]  LN over T (ddof=1) -> QK GEMM + V^T GEMM -> causal flash
//   attn (split-s flash-decoding, dbuf LDS, swizzled global_load_lds) + merge
//   -> +resid -> LN -> MLP -> +resid
// GEMMs: 512-thr 8-wave (32x32/wave), BK=64, dbuf, counted vmcnt(3), XOR-swz
//        LDS (both-sides involution), XCD swizzle.
// Attn: scale folded into Wq; defer-max fast path; deferred l-reduce.
// ---------------------------------------------------------------------------

typedef __bf16 bf16x8 __attribute__((ext_vector_type(8)));
typedef float f32x4 __attribute__((ext_vector_type(4)));
typedef unsigned short u16;
typedef u16 u16x8 __attribute__((ext_vector_type(8)));
typedef u16 u16x4 __attribute__((ext_vector_type(4)));

#define MFMA16 __builtin_amdgcn_mfma_f32_16x16x32_bf16

__device__ __forceinline__ u16 f2bf(float f) {  // native v_cvt (RNE)
  return __builtin_bit_cast(u16, (__bf16)f);
}
__device__ __forceinline__ float bf2f(u16 u) {
  return __builtin_bit_cast(float, (unsigned)u << 16);
}
__device__ __forceinline__ bf16x8 ldbf8(const u16* p) {
  return __builtin_bit_cast(bf16x8, *reinterpret_cast<const u16x8*>(p));
}
// async global->LDS, 16B per lane, dest = wave-uniform base + lane*16
__device__ __forceinline__ void gll16(const void* g, void* l) {
  __builtin_amdgcn_global_load_lds((const __attribute__((address_space(1))) void*)g,
                                   (__attribute__((address_space(3))) void*)l, 16, 0, 0);
}
template <int N>
__device__ __forceinline__ void wait_vm() {
  if constexpr (N == 0)      asm volatile("s_waitcnt vmcnt(0)" ::: "memory");
  else if constexpr (N == 3) asm volatile("s_waitcnt vmcnt(3)" ::: "memory");
  else if constexpr (N == 4) asm volatile("s_waitcnt vmcnt(4)" ::: "memory");
  else                       asm volatile("s_waitcnt vmcnt(6)" ::: "memory");
}
__device__ __forceinline__ void barrier_raw() {
  asm volatile("" ::: "memory");
  __builtin_amdgcn_s_barrier();
  asm volatile("" ::: "memory");
}

// ---------------- weight transpose (f32 [K][N] -> bf16 [N][K]) -------------
__global__ __launch_bounds__(256) void transpose_big(const float* __restrict__ in,
                                                     u16* __restrict__ out, int K, int N) {
  __shared__ float tile[64][65];
  const int k0 = blockIdx.x * 64, n0 = blockIdx.y * 64;
  const int c = threadIdx.x & 63, rg = threadIdx.x >> 6;
#pragma unroll
  for (int i = 0; i < 16; ++i) {
    int r = rg * 16 + i;
    tile[r][c] = in[(size_t)(k0 + r) * N + n0 + c];
  }
  __syncthreads();
#pragma unroll
  for (int i = 0; i < 16; ++i) {
    int nl = rg * 16 + i;
    out[(size_t)(n0 + nl) * K + k0 + c] = f2bf(tile[c][nl]);
  }
}

// Wq/Wk/Wv: [H][1024][64] f32 -> rows (zoff + h*64 + d) of [3072][1024] bf16.
// scale folds softmax scaling into Wq (Q pre-scaled by C^-0.5 * log2 e).
__global__ __launch_bounds__(256) void transpose_head(const float* __restrict__ W,
                                                      u16* __restrict__ out, int zoff,
                                                      float scale) {
  __shared__ float tile[64][65];
  const int k0 = blockIdx.x * 64, h = blockIdx.y;
  const float* in = W + (size_t)h * 1024 * 64;
  const int c = threadIdx.x & 63, rg = threadIdx.x >> 6;
#pragma unroll
  for (int i = 0; i < 16; ++i) {
    int r = rg * 16 + i;
    tile[r][c] = in[(size_t)(k0 + r) * 64 + c];
  }
  __syncthreads();
#pragma unroll
  for (int i = 0; i < 16; ++i) {
    int nl = rg * 16 + i;
    out[(size_t)(zoff + h * 64 + nl) * 1024 + k0 + c] = f2bf(tile[c][nl] * scale);
  }
}

// ---------------- LayerNorm over sequence axis T (per (b,c)) ---------------
__global__ __launch_bounds__(256) void ln_partial(const float* __restrict__ x,
                                                  float2* __restrict__ part) {
  const int b = blockIdx.x >> 4, c0 = (blockIdx.x & 15) * 64;
  const int c = c0 + (threadIdx.x & 63), tg = threadIdx.x >> 6;
  const int t0 = blockIdx.y * 256 + tg * 64;
  float s = 0.f, sq = 0.f;
  const float* p = x + (size_t)(b * 2048 + t0) * 1024 + c;
#pragma unroll 8
  for (int i = 0; i < 64; ++i) {
    float v = p[(size_t)i * 1024];
    s += v; sq += v * v;
  }
  __shared__ float ss[256], sb[256];
  ss[threadIdx.x] = s; sb[threadIdx.x] = sq;
  __syncthreads();
  if (threadIdx.x < 64) {
    s  = ss[threadIdx.x] + ss[threadIdx.x + 64] + ss[threadIdx.x + 128] + ss[threadIdx.x + 192];
    sq = sb[threadIdx.x] + sb[threadIdx.x + 64] + sb[threadIdx.x + 128] + sb[threadIdx.x + 192];
    part[(size_t)(b * 1024 + c) * 8 + blockIdx.y] = make_float2(s, sq);
  }
}

__global__ __launch_bounds__(256) void ln_stats(const float2* __restrict__ part,
                                                float2* __restrict__ stats) {
  const int bc = blockIdx.x * 256 + threadIdx.x;
  float s = 0.f, sq = 0.f;
#pragma unroll
  for (int i = 0; i < 8; ++i) {
    float2 v = part[(size_t)bc * 8 + i];
    s += v.x; sq += v.y;
  }
  const float mean = s * (1.0f / 2048.0f);
  const float var = (sq - 2048.0f * mean * mean) * (1.0f / 2047.0f);  // ddof=1
  stats[bc] = make_float2(mean, rsqrtf(var + 1e-5f));
}

__global__ __launch_bounds__(256) void ln_apply(const float* __restrict__ x,
                                                const float2* __restrict__ stats,
                                                const float* __restrict__ g,
                                                const float* __restrict__ be,
                                                u16* __restrict__ out) {
  const size_t flat = ((size_t)blockIdx.x * 256 + threadIdx.x) * 4;
  const int b = (int)(flat >> 21);
  const int c = (int)(flat & 1023);
  float4 xv = *reinterpret_cast<const float4*>(x + flat);
  float vs[4] = {xv.x, xv.y, xv.z, xv.w};
  u16x4 o;
#pragma unroll
  for (int j = 0; j < 4; ++j) {
    float2 st = stats[b * 1024 + c + j];
    o[j] = f2bf(g[c + j] * (vs[j] - st.x) * st.y + be[c + j]);
  }
  *reinterpret_cast<u16x4*>(out + flat) = o;
}

// ---------------- GEMM: C = A[M,K] x Bt[N,K]^T -----------------------------
// 512 threads, WM x WN waves of 32x32 each. BK=64. Double-buffered, counted
// vmcnt (prefetch stays in flight across barriers). LDS XOR-swizzled at 16B
// granules: source pre-swizzled (lane&7)^(lane>>3), read (kk*4+lg)^(lr&7).
// EPI 0: store bf16.  1: +bias, ReLU, bf16.  2: +bias +resid, f32.
template <int WM, int WN, int EPI>
__global__ __launch_bounds__(512, 6) void gemm_kernel(const u16* __restrict__ A,
                                                      const u16* __restrict__ Bt,
                                                      u16* __restrict__ outb,
                                                      float* __restrict__ outf,
                                                      const float* __restrict__ bias,
                                                      const float* __restrict__ resid,
                                                      int N, int K) {
  constexpr int BM = WM * 32, BN = WN * 32;
  constexpr int ACH = BM / 8;          // A chunks (8 rows of 64 u16 each)
  constexpr int TC = (BM + BN) / 8;    // total chunks
  constexpr int LPW = TC / 8;          // gll16 per wave per stage
  static_assert(TC % 8 == 0, "chunks must divide evenly over 8 waves");
  __shared__ alignas(16) u16 sA[2][BM * 64];
  __shared__ alignas(16) u16 sB[2][BN * 64];
  // T1: XCD swizzle (valid: all grids have nwg % 8 == 0)
  const int gx = gridDim.x;
  const int nwg = gx * gridDim.y;
  int bid = blockIdx.y * gx + blockIdx.x;
  bid = (bid & 7) * (nwg >> 3) + (bid >> 3);
  const int n0 = (bid % gx) * BN, m0 = (bid / gx) * BM;
  const int tid = threadIdx.x, lane = tid & 63, wid = tid >> 6;
  const int wm = (wid / WN) * 32, wn = (wid % WN) * 32;
  const int lr = lane & 15, lg = lane >> 4;
  const int srow = lane >> 3;                 // row within 8-row chunk
  const int sgr = (lane & 7) ^ srow;          // pre-swizzled source granule
  const int x7 = lr & 7;                      // read-side swizzle key
  f32x4 acc[2][2] = {};

  auto stage = [&](int buf, int k0) {
#pragma unroll
    for (int i = 0; i < LPW; ++i) {
      const int c = wid * LPW + i;
      if (c < ACH) {
        const int r = c * 8 + srow;
        gll16(A + (size_t)(m0 + r) * K + k0 + sgr * 8, &sA[buf][c * 512]);
      } else {
        const int r = (c - ACH) * 8 + srow;
        gll16(Bt + (size_t)(n0 + r) * K + k0 + sgr * 8, &sB[buf][(c - ACH) * 512]);
      }
    }
  };

  const int nsteps = K >> 6;
  stage(0, 0);
  int cur = 0;
  for (int t = 0; t < nsteps; ++t) {
    if (t + 1 < nsteps) {
      stage(cur ^ 1, (t + 1) * 64);  // prefetch stays in flight across barriers
      wait_vm<LPW>();                // tile t landed (its LPW loads are oldest)
    } else {
      wait_vm<0>();
    }
    barrier_raw();
    bf16x8 af[2][2], bfr[2][2];
#pragma unroll
    for (int mi = 0; mi < 2; ++mi)
#pragma unroll
      for (int kk = 0; kk < 2; ++kk)
        af[mi][kk] = ldbf8(&sA[cur][(wm + mi * 16 + lr) * 64 + (((kk * 4 + lg) ^ x7) * 8)]);
#pragma unroll
    for (int ni = 0; ni < 2; ++ni)
#pragma unroll
      for (int kk = 0; kk < 2; ++kk)
        bfr[ni][kk] = ldbf8(&sB[cur][(wn + ni * 16 + lr) * 64 + (((kk * 4 + lg) ^ x7) * 8)]);
#pragma unroll
    for (int kk = 0; kk < 2; ++kk)
#pragma unroll
      for (int mi = 0; mi < 2; ++mi)
#pragma unroll
        for (int ni = 0; ni < 2; ++ni)
          acc[mi][ni] = MFMA16(af[mi][kk], bfr[ni][kk], acc[mi][ni], 0, 0, 0);
    barrier_raw();                   // WAR: reads done before next overwrite
    cur ^= 1;
  }

#pragma unroll
  for (int mi = 0; mi < 2; ++mi)
#pragma unroll
    for (int ni = 0; ni < 2; ++ni)
#pragma unroll
      for (int r = 0; r < 4; ++r) {
        const int row = m0 + wm + mi * 16 + lg * 4 + r;   // C/D: row=(lane>>4)*4+reg
        const int col = n0 + wn + ni * 16 + lr;           //      col=lane&15
        float v = acc[mi][ni][r];
        if (EPI == 0) {
          outb[(size_t)row * N + col] = f2bf(v);
        } else if (EPI == 1) {
          v += bias[col];
          v = fmaxf(v, 0.f);
          outb[(size_t)row * N + col] = f2bf(v);
        } else {
          v += bias[col] + resid[(size_t)row * N + col];
          outf[(size_t)row * N + col] = v;
        }
      }
}

// ---------------- causal flash attention: split-s partial pass -------------
// qk: bf16 [4096 tok][2048] (Q|K per head), Q pre-scaled to exp2 domain.
// vt: bf16 [1024 hd][4096 tok].
__global__ __launch_bounds__(256) void attn_partial(const u16* __restrict__ qk,
                                                    const u16* __restrict__ vt,
                                                    u16* __restrict__ Opart,
                                                    float2* __restrict__ ml) {
  const int xr = 79 - (int)blockIdx.x;  // heavy (long-range) blocks first
  int qb, ch, nc;
  if (xr < 8)       { qb = xr;                ch = 0;            nc = 1; }
  else if (xr < 24) { qb = 8 + ((xr - 8) >> 1);  ch = (xr - 8) & 1;  nc = 2; }
  else if (xr < 48) { qb = 16 + (xr - 24) / 3;   ch = (xr - 24) % 3; nc = 3; }
  else              { qb = 24 + ((xr - 48) >> 2); ch = (xr - 48) & 3; nc = 4; }
  const int nt_tot = qb + 1;
  const int t0 = (ch * nt_tot) / nc;
  const int t1 = ((ch + 1) * nt_tot) / nc;
  const int bh = blockIdx.y, b = bh >> 4, h = bh & 15;
  const int slot = bh * 80 + xr;
  const int q0 = qb * 64;
  const int tid = threadIdx.x, lane = tid & 63, w = tid >> 6;
  const int lr = lane & 15, lg = lane >> 4;
  __shared__ alignas(16) u16 sK[2][64 * 64];   // [s][d], 16B-granule XOR swizzle
  __shared__ alignas(16) u16 sV[2][64 * 64];   // [d][s], same swizzle
  __shared__ alignas(16) u16 sP[4][16 * 64];   // per-wave P, XOR-swizzled

  const size_t qrow = (size_t)(b * 2048 + q0 + w * 16 + lr) * 2048 + h * 64;
  const bf16x8 aq0 = ldbf8(qk + qrow + lg * 8);
  const bf16x8 aq1 = ldbf8(qk + qrow + 32 + lg * 8);

  float m_i[4], l_i[4];   // l_i: PER-LANE partial sums (reduced in epilogue)
  f32x4 acc[4];
#pragma unroll
  for (int r = 0; r < 4; ++r) { m_i[r] = -1e30f; l_i[r] = 0.f; }
#pragma unroll
  for (int dn = 0; dn < 4; ++dn) acc[dn] = f32x4{0.f, 0.f, 0.f, 0.f};

  auto stage = [&](int buf, int s0) {
#pragma unroll
    for (int i = 0; i < 2; ++i) {
      const int c = w * 2 + i;
      const int g = c * 64 + lane;
      const int row = g >> 3;
      const int cs = (g & 7) ^ (row & 7);
      gll16(qk + (size_t)(b * 2048 + s0 + row) * 2048 + 1024 + h * 64 + cs * 8,
            &sK[buf][c * 512]);
      gll16(vt + (size_t)(h * 64 + row) * 4096 + b * 2048 + s0 + cs * 8,
            &sV[buf][c * 512]);
    }
  };

  stage(0, t0 * 64);

  for (int t = t0; t < t1; ++t) {
    const int buf = (t - t0) & 1;
    if (t + 1 < t1) {
      stage(buf ^ 1, (t + 1) * 64);
      wait_vm<4>();
    } else {
      wait_vm<0>();
    }
    barrier_raw();

    const u16* Kb = sK[buf];
    const u16* Vb = sV[buf];
    f32x4 sf[4];
    __builtin_amdgcn_s_setprio(1);
#pragma unroll
    for (int sn = 0; sn < 4; ++sn) {  // S[16q x 64s] = Q . K^T (exp2 domain)
      const int row = sn * 16 + lr;
      const int x7 = lr & 7;
      bf16x8 k0f = ldbf8(&Kb[row * 64 + ((lg ^ x7) * 8)]);
      bf16x8 k1f = ldbf8(&Kb[row * 64 + (((4 + lg) ^ x7) * 8)]);
      f32x4 z = {0.f, 0.f, 0.f, 0.f};
      z = MFMA16(aq0, k0f, z, 0, 0, 0);
      z = MFMA16(aq1, k1f, z, 0, 0, 0);
      sf[sn] = z;
    }
    __builtin_amdgcn_s_setprio(0);

    if (t == nt_tot - 1) {  // causal mask (last tile only)
      const int qlb = w * 16 + lg * 4;
#pragma unroll
      for (int sn = 0; sn < 4; ++sn)
#pragma unroll
        for (int r = 0; r < 4; ++r)
          if (sn * 16 + lr > qlb + r) sf[sn][r] = -1e30f;
    }

    // defer-max fast path: full reduce+rescale only when growth > 8
    float pm[4];
    bool need = false;
#pragma unroll
    for (int r = 0; r < 4; ++r) {
      pm[r] = fmaxf(fmaxf(sf[0][r], sf[1][r]), fmaxf(sf[2][r], sf[3][r]));
      need = need || (pm[r] > m_i[r] + 8.f);
    }
    if (__any(need)) {
#pragma unroll
      for (int r = 0; r < 4; ++r) {
        float mx = pm[r];
        mx = fmaxf(mx, __shfl_xor(mx, 1, 16));
        mx = fmaxf(mx, __shfl_xor(mx, 2, 16));
        mx = fmaxf(mx, __shfl_xor(mx, 4, 16));
        mx = fmaxf(mx, __shfl_xor(mx, 8, 16));
        const float mnew = fmaxf(m_i[r], mx);
        const float al = exp2f(m_i[r] - mnew);
        l_i[r] *= al;
        acc[0][r] *= al; acc[1][r] *= al; acc[2][r] *= al; acc[3][r] *= al;
        m_i[r] = mnew;
      }
    }

    // P = exp2(S - m); per-lane l accumulation; swizzled P store
    const int x7p = lr & 7;
#pragma unroll
    for (int r = 0; r < 4; ++r) {
      const float p0 = exp2f(sf[0][r] - m_i[r]), p1 = exp2f(sf[1][r] - m_i[r]);
      const float p2 = exp2f(sf[2][r] - m_i[r]), p3 = exp2f(sf[3][r] - m_i[r]);
      l_i[r] += (p0 + p1) + (p2 + p3);
      const int prow = lg * 4 + r;
      const int pb = prow * 64, px = prow & 7;
      sP[w][pb + (((lr >> 3) ^ px) * 8) + (lr & 7)]       = f2bf(p0);
      sP[w][pb + (((2 + (lr >> 3)) ^ px) * 8) + (lr & 7)] = f2bf(p1);
      sP[w][pb + (((4 + (lr >> 3)) ^ px) * 8) + (lr & 7)] = f2bf(p2);
      sP[w][pb + (((6 + (lr >> 3)) ^ px) * 8) + (lr & 7)] = f2bf(p3);
    }

    // O += P . V   (wave-local P; compiler inserts lgkmcnt for the RAW)
    const bf16x8 pa0 = ldbf8(&sP[w][lr * 64 + ((lg ^ x7p) * 8)]);
    const bf16x8 pa1 = ldbf8(&sP[w][lr * 64 + (((4 + lg) ^ x7p) * 8)]);
    __builtin_amdgcn_s_setprio(1);
#pragma unroll
    for (int dn = 0; dn < 4; ++dn) {
      const int row = dn * 16 + lr;
      bf16x8 v0f = ldbf8(&Vb[row * 64 + ((lg ^ x7p) * 8)]);
      bf16x8 v1f = ldbf8(&Vb[row * 64 + (((4 + lg) ^ x7p) * 8)]);
      acc[dn] = MFMA16(pa0, v0f, acc[dn], 0, 0, 0);
      acc[dn] = MFMA16(pa1, v1f, acc[dn], 0, 0, 0);
    }
    __builtin_amdgcn_s_setprio(0);
    barrier_raw();  // WAR guard before next stage overwrites
  }

  // partial epilogue: reduce per-lane l, write unnormalized O (bf16) + (m,l)
  const int rbase = w * 16 + lg * 4;
#pragma unroll
  for (int r = 0; r < 4; ++r) {
    float ls = l_i[r];
    ls += __shfl_xor(ls, 1, 16);
    ls += __shfl_xor(ls, 2, 16);
    ls += __shfl_xor(ls, 4, 16);
    ls += __shfl_xor(ls, 8, 16);
    const int row = rbase + r;
    if (lr == 0) ml[(size_t)slot * 64 + row] = make_float2(m_i[r], ls);
#pragma unroll
    for (int dn = 0; dn < 4; ++dn)
      Opart[((size_t)slot * 64 + row) * 64 + dn * 16 + lr] = f2bf(acc[dn][r]);
  }
}

// ---------------- attention merge + residual -------------------------------
__global__ __launch_bounds__(256) void attn_merge(const u16* __restrict__ Opart,
                                                  const float2* __restrict__ ml,
                                                  const float* __restrict__ x,
                                                  float* __restrict__ x2) {
  const int qb = blockIdx.x, bh = blockIdx.y, b = bh >> 4, h = bh & 15;
  int nc, s0;
  if (qb < 8)       { nc = 1; s0 = qb; }
  else if (qb < 16) { nc = 2; s0 = 8 + (qb - 8) * 2; }
  else if (qb < 24) { nc = 3; s0 = 24 + (qb - 16) * 3; }
  else              { nc = 4; s0 = 48 + (qb - 24) * 4; }
  const size_t slot0 = (size_t)bh * 80 + s0;
  const int tid = threadIdx.x;
  const int row = tid >> 2, d0 = (tid & 3) * 16;

  float wgt[4];
  float mmax = -1e30f, lsum = 0.f;
  for (int i = 0; i < nc; ++i) {
    float2 v = ml[(slot0 + i) * 64 + row];
    wgt[i] = v.x;
    mmax = fmaxf(mmax, v.x);
  }
  for (int i = 0; i < nc; ++i) {
    float2 v = ml[(slot0 + i) * 64 + row];
    wgt[i] = exp2f(wgt[i] - mmax);
    lsum += wgt[i] * v.y;
  }
  const float inv = 1.0f / lsum;

#pragma unroll
  for (int half = 0; half < 2; ++half) {
    const int d = d0 + half * 8;
    float o[8] = {0.f, 0.f, 0.f, 0.f, 0.f, 0.f, 0.f, 0.f};
    for (int i = 0; i < nc; ++i) {
      u16x8 v = *reinterpret_cast<const u16x8*>(&Opart[((slot0 + i) * 64 + row) * 64 + d]);
#pragma unroll
      for (int j = 0; j < 8; ++j) o[j] += wgt[i] * bf2f(v[j]);
    }
    const size_t idx = ((size_t)(b * 2048 + qb * 64 + row)) * 1024 + h * 64 + d;
    float4 x0 = *reinterpret_cast<const float4*>(x + idx);
    float4 x1 = *reinterpret_cast<const float4*>(x + idx + 4);
    float4 o0 = make_float4(x0.x + o[0] * inv, x0.y + o[1] * inv, x0.z + o[2] * inv, x0.w + o[3] * inv);
    float4 o1 = make_float4(x1.x + o[4] * inv, x1.y + o[5] * inv, x1.z + o[6] * inv, x1.w + o[7] * inv);
    *reinterpret_cast<float4*>(x2 + idx) = o0;
    *reinterpret_cast<float4*>(x2 + idx + 4) = o1;
  }
}

// ---------------------------------------------------------------------------
extern "C" void kernel_launch(void* const* d_in, const int* in_sizes, int n_in,
                              void* d_out, int out_size, void* d_ws, size_t ws_size,
                              hipStream_t stream) {
  const float* x   = (const float*)d_in[0];
  const float* Wq  = (const float*)d_in[1];
  const float* Wk  = (const float*)d_in[2];
  const float* Wv  = (const float*)d_in[3];
  const float* W1  = (const float*)d_in[4];
  const float* b1  = (const float*)d_in[5];
  const float* W2  = (const float*)d_in[6];
  const float* b2  = (const float*)d_in[7];
  const float* g1  = (const float*)d_in[8];
  const float* be1 = (const float*)d_in[9];
  const float* g2  = (const float*)d_in[10];
  const float* be2 = (const float*)d_in[11];
  float* out = (float*)d_out;

  char* ws = (char*)d_ws;
  size_t off = 0;
  auto alloc = [&](size_t bytes) { char* p = ws + off; off += (bytes + 255) & ~(size_t)255; return p; };
  u16*    qkb   = (u16*)alloc(4096ull * 2048 * 2);   // [tok][Q|K]          16MB
  u16*    vtb   = (u16*)alloc(1024ull * 4096 * 2);   // [hd][tok]            8MB
  (void)alloc(4096ull * 1024 * 2);                   // h1 overflow region   8MB
  u16*    h1    = qkb;                               // MLP1 out aliases qk+vt+overflow (32MB)
  float*  x2    = (float*)alloc(4096ull * 1024 * 4); // x + attn            16MB
  u16*    hbuf  = (u16*)alloc(4096ull * 1024 * 2);   // LN outputs           8MB
  u16*    wqkvt = (u16*)alloc(3072ull * 1024 * 2);
  u16*    w1t   = (u16*)alloc(4096ull * 1024 * 2);
  u16*    w2t   = (u16*)alloc(1024ull * 4096 * 2);
  float2* part  = (float2*)alloc(2048ull * 8 * 8);
  float2* stats = (float2*)alloc(2048ull * 8);
  u16*    Opart = (u16*)alloc(32ull * 80 * 64 * 64 * 2);   // ~21MB
  float2* ml    = (float2*)alloc(32ull * 80 * 64 * 8);     // ~1.3MB
  (void)ws_size; (void)in_sizes; (void)n_in; (void)out_size;

  // weight prep (bf16, B-transposed); softmax scale folded into Wq
  const float SC = 0.03125f * 1.44269504088896341f;  // C^-0.5 * log2(e)
  transpose_head<<<dim3(16, 16), 256, 0, stream>>>(Wq, wqkvt, 0, SC);
  transpose_head<<<dim3(16, 16), 256, 0, stream>>>(Wk, wqkvt, 1024, 1.0f);
  transpose_head<<<dim3(16, 16), 256, 0, stream>>>(Wv, wqkvt, 2048, 1.0f);
  transpose_big<<<dim3(16, 64), 256, 0, stream>>>(W1, w1t, 1024, 4096);
  transpose_big<<<dim3(64, 16), 256, 0, stream>>>(W2, w2t, 4096, 1024);

  // LN1 (over T) -> hbuf
  ln_partial<<<dim3(32, 8), 256, 0, stream>>>(x, part);
  ln_stats<<<8, 256, 0, stream>>>(part, stats);
  ln_apply<<<4096, 256, 0, stream>>>(x, stats, g1, be1, hbuf);

  // QK GEMM: [4096,1024] x W_qk^T -> qkb [4096][2048]   (BM128 BN64)
  gemm_kernel<4, 2, 0><<<dim3(32, 32), 512, 0, stream>>>(hbuf, wqkvt, qkb, nullptr, nullptr, nullptr, 2048, 1024);
  // V^T GEMM: Wv^T [1024,1024] x LN1^T -> vtb [1024][4096]   (BM64 BN128)
  gemm_kernel<2, 4, 0><<<dim3(32, 16), 512, 0, stream>>>(wqkvt + 2048 * 1024, hbuf, vtb, nullptr, nullptr, nullptr, 4096, 1024);

  // attention: split-s partials, then merge + residual -> x2 (f32)
  attn_partial<<<dim3(80, 32), 256, 0, stream>>>(qkb, vtb, Opart, ml);
  attn_merge<<<dim3(32, 32), 256, 0, stream>>>(Opart, ml, x, x2);

  // LN2 (over T) -> hbuf
  ln_partial<<<dim3(32, 8), 256, 0, stream>>>(x2, part);
  ln_stats<<<8, 256, 0, stream>>>(part, stats);
  ln_apply<<<4096, 256, 0, stream>>>(x2, stats, g2, be2, hbuf);

  // MLP1: relu(h @ W1 + b1) -> h1 (bf16 [4096][4096])   (BM128 BN64)
  gemm_kernel<4, 2, 1><<<dim3(64, 32), 512, 0, stream>>>(hbuf, w1t, h1, nullptr, b1, nullptr, 4096, 1024);

  // MLP2: x2 + h1 @ W2 + b2 -> out (f32)   (BM128 BN64)
  gemm_kernel<4, 2, 2><<<dim3(16, 32), 512, 0, stream>>>(h1, w2t, nullptr, out, b2, x2, 1024, 4096);
}

// Round 7
// 255.001 us; speedup vs baseline: 1.7848x; 1.0583x over previous
//
#include <hip/hip_runtime.h>

// ---------------------------------------------------------------------------
// Transformer block on MI355X (gfx950), bf16 MFMA pipeline, fp32 residual/LN.
//   x:[2,2048,1024]  LN over T (ddof=1) -> QK GEMM + V^T GEMM -> causal flash
//   attn (split-s flash-decoding, dbuf LDS, swizzled global_load_lds) + merge
//   -> +resid -> LN -> MLP -> +resid
// GEMMs: 256-thr 4-wave, 64x64 wave tile (2:1 MFMA:ds_read), BM=BN=128 BK=64,
//        dbuf + counted vmcnt(8), XOR-swz LDS, XCD swizzle, 2 blocks/CU.
// Attn: scale folded into Wq; defer-max fast path; deferred l-reduce.
// ---------------------------------------------------------------------------

typedef __bf16 bf16x8 __attribute__((ext_vector_type(8)));
typedef float f32x4 __attribute__((ext_vector_type(4)));
typedef unsigned short u16;
typedef u16 u16x8 __attribute__((ext_vector_type(8)));
typedef u16 u16x4 __attribute__((ext_vector_type(4)));

#define MFMA16 __builtin_amdgcn_mfma_f32_16x16x32_bf16

__device__ __forceinline__ u16 f2bf(float f) {  // native v_cvt (RNE)
  return __builtin_bit_cast(u16, (__bf16)f);
}
__device__ __forceinline__ float bf2f(u16 u) {
  return __builtin_bit_cast(float, (unsigned)u << 16);
}
__device__ __forceinline__ bf16x8 ldbf8(const u16* p) {
  return __builtin_bit_cast(bf16x8, *reinterpret_cast<const u16x8*>(p));
}
// async global->LDS, 16B per lane, dest = wave-uniform base + lane*16
__device__ __forceinline__ void gll16(const void* g, void* l) {
  __builtin_amdgcn_global_load_lds((const __attribute__((address_space(1))) void*)g,
                                   (__attribute__((address_space(3))) void*)l, 16, 0, 0);
}
template <int N>
__device__ __forceinline__ void wait_vm() {
  if constexpr (N == 0)      asm volatile("s_waitcnt vmcnt(0)" ::: "memory");
  else if constexpr (N == 4) asm volatile("s_waitcnt vmcnt(4)" ::: "memory");
  else if constexpr (N == 8) asm volatile("s_waitcnt vmcnt(8)" ::: "memory");
  else                       asm volatile("s_waitcnt vmcnt(16)" ::: "memory");
}
__device__ __forceinline__ void barrier_raw() {
  asm volatile("" ::: "memory");
  __builtin_amdgcn_s_barrier();
  asm volatile("" ::: "memory");
}

// ---------------- weight transpose (f32 [K][N] -> bf16 [N][K]) -------------
__global__ __launch_bounds__(256) void transpose_big(const float* __restrict__ in,
                                                     u16* __restrict__ out, int K, int N) {
  __shared__ float tile[64][65];
  const int k0 = blockIdx.x * 64, n0 = blockIdx.y * 64;
  const int c = threadIdx.x & 63, rg = threadIdx.x >> 6;
#pragma unroll
  for (int i = 0; i < 16; ++i) {
    int r = rg * 16 + i;
    tile[r][c] = in[(size_t)(k0 + r) * N + n0 + c];
  }
  __syncthreads();
#pragma unroll
  for (int i = 0; i < 16; ++i) {
    int nl = rg * 16 + i;
    out[(size_t)(n0 + nl) * K + k0 + c] = f2bf(tile[c][nl]);
  }
}

// Wq/Wk/Wv: [H][1024][64] f32 -> rows (zoff + h*64 + d) of [3072][1024] bf16.
// scale folds softmax scaling into Wq (Q pre-scaled by C^-0.5 * log2 e).
__global__ __launch_bounds__(256) void transpose_head(const float* __restrict__ W,
                                                      u16* __restrict__ out, int zoff,
                                                      float scale) {
  __shared__ float tile[64][65];
  const int k0 = blockIdx.x * 64, h = blockIdx.y;
  const float* in = W + (size_t)h * 1024 * 64;
  const int c = threadIdx.x & 63, rg = threadIdx.x >> 6;
#pragma unroll
  for (int i = 0; i < 16; ++i) {
    int r = rg * 16 + i;
    tile[r][c] = in[(size_t)(k0 + r) * 64 + c];
  }
  __syncthreads();
#pragma unroll
  for (int i = 0; i < 16; ++i) {
    int nl = rg * 16 + i;
    out[(size_t)(zoff + h * 64 + nl) * 1024 + k0 + c] = f2bf(tile[c][nl] * scale);
  }
}

// ---------------- LayerNorm over sequence axis T (per (b,c)) ---------------
__global__ __launch_bounds__(256) void ln_partial(const float* __restrict__ x,
                                                  float2* __restrict__ part) {
  const int b = blockIdx.x >> 4, c0 = (blockIdx.x & 15) * 64;
  const int c = c0 + (threadIdx.x & 63), tg = threadIdx.x >> 6;
  const int t0 = blockIdx.y * 256 + tg * 64;
  float s = 0.f, sq = 0.f;
  const float* p = x + (size_t)(b * 2048 + t0) * 1024 + c;
#pragma unroll 8
  for (int i = 0; i < 64; ++i) {
    float v = p[(size_t)i * 1024];
    s += v; sq += v * v;
  }
  __shared__ float ss[256], sb[256];
  ss[threadIdx.x] = s; sb[threadIdx.x] = sq;
  __syncthreads();
  if (threadIdx.x < 64) {
    s  = ss[threadIdx.x] + ss[threadIdx.x + 64] + ss[threadIdx.x + 128] + ss[threadIdx.x + 192];
    sq = sb[threadIdx.x] + sb[threadIdx.x + 64] + sb[threadIdx.x + 128] + sb[threadIdx.x + 192];
    part[(size_t)(b * 1024 + c) * 8 + blockIdx.y] = make_float2(s, sq);
  }
}

__global__ __launch_bounds__(256) void ln_stats(const float2* __restrict__ part,
                                                float2* __restrict__ stats) {
  const int bc = blockIdx.x * 256 + threadIdx.x;
  float s = 0.f, sq = 0.f;
#pragma unroll
  for (int i = 0; i < 8; ++i) {
    float2 v = part[(size_t)bc * 8 + i];
    s += v.x; sq += v.y;
  }
  const float mean = s * (1.0f / 2048.0f);
  const float var = (sq - 2048.0f * mean * mean) * (1.0f / 2047.0f);  // ddof=1
  stats[bc] = make_float2(mean, rsqrtf(var + 1e-5f));
}

__global__ __launch_bounds__(256) void ln_apply(const float* __restrict__ x,
                                                const float2* __restrict__ stats,
                                                const float* __restrict__ g,
                                                const float* __restrict__ be,
                                                u16* __restrict__ out) {
  const size_t flat = ((size_t)blockIdx.x * 256 + threadIdx.x) * 4;
  const int b = (int)(flat >> 21);
  const int c = (int)(flat & 1023);
  float4 xv = *reinterpret_cast<const float4*>(x + flat);
  float vs[4] = {xv.x, xv.y, xv.z, xv.w};
  u16x4 o;
#pragma unroll
  for (int j = 0; j < 4; ++j) {
    float2 st = stats[b * 1024 + c + j];
    o[j] = f2bf(g[c + j] * (vs[j] - st.x) * st.y + be[c + j]);
  }
  *reinterpret_cast<u16x4*>(out + flat) = o;
}

// ---------------- GEMM: C = A[M,K] x Bt[N,K]^T -----------------------------
// 256 threads / 4 waves (2x2), wave tile 64x64 -> 32 MFMA per 16 ds_read per
// K-64 step. BM=BN=128. Double-buffered, counted vmcnt(8). LDS XOR-swizzled
// at 16B granules: source pre-swz (lane&7)^(lane>>3), read (kk*4+lg)^(lr&7).
// EPI 0: store bf16.  1: +bias, ReLU, bf16.  2: +bias +resid, f32.
template <int EPI>
__global__ __launch_bounds__(256, 2) void gemm_kernel(const u16* __restrict__ A,
                                                      const u16* __restrict__ Bt,
                                                      u16* __restrict__ outb,
                                                      float* __restrict__ outf,
                                                      const float* __restrict__ bias,
                                                      const float* __restrict__ resid,
                                                      int N, int K) {
  constexpr int BM = 128, BN = 128;
  __shared__ alignas(16) u16 sA[2][BM * 64];   // 32 KB
  __shared__ alignas(16) u16 sB[2][BN * 64];   // 32 KB
  // T1: XCD swizzle (valid: all grids have nwg % 8 == 0)
  const int gx = gridDim.x;
  const int nwg = gx * gridDim.y;
  int bid = blockIdx.y * gx + blockIdx.x;
  bid = (bid & 7) * (nwg >> 3) + (bid >> 3);
  const int n0 = (bid % gx) * BN, m0 = (bid / gx) * BM;
  const int tid = threadIdx.x, lane = tid & 63, wid = tid >> 6;
  const int wm = (wid >> 1) * 64, wn = (wid & 1) * 64;
  const int lr = lane & 15, lg = lane >> 4;
  const int srow = lane >> 3;                 // row within 8-row chunk
  const int sgr = (lane & 7) ^ srow;          // pre-swizzled source granule
  const int x7 = lr & 7;                      // read-side swizzle key
  f32x4 acc[4][4] = {};

  // 32 chunks of 8 rows x 128B; 8 gll16 per wave per stage
  auto stage = [&](int buf, int k0) {
#pragma unroll
    for (int i = 0; i < 8; ++i) {
      const int c = wid * 8 + i;
      if (c < 16) {
        const int r = c * 8 + srow;
        gll16(A + (size_t)(m0 + r) * K + k0 + sgr * 8, &sA[buf][c * 512]);
      } else {
        const int r = (c - 16) * 8 + srow;
        gll16(Bt + (size_t)(n0 + r) * K + k0 + sgr * 8, &sB[buf][(c - 16) * 512]);
      }
    }
  };

  const int nsteps = K >> 6;
  stage(0, 0);
  int cur = 0;
  for (int t = 0; t < nsteps; ++t) {
    if (t + 1 < nsteps) {
      stage(cur ^ 1, (t + 1) * 64);  // prefetch stays in flight across barriers
      wait_vm<8>();                  // tile t's 8 loads (oldest) have landed
    } else {
      wait_vm<0>();
    }
    barrier_raw();
    bf16x8 af[4][2], bfr[4][2];
#pragma unroll
    for (int mi = 0; mi < 4; ++mi)
#pragma unroll
      for (int kk = 0; kk < 2; ++kk)
        af[mi][kk] = ldbf8(&sA[cur][(wm + mi * 16 + lr) * 64 + (((kk * 4 + lg) ^ x7) * 8)]);
#pragma unroll
    for (int ni = 0; ni < 4; ++ni)
#pragma unroll
      for (int kk = 0; kk < 2; ++kk)
        bfr[ni][kk] = ldbf8(&sB[cur][(wn + ni * 16 + lr) * 64 + (((kk * 4 + lg) ^ x7) * 8)]);
#pragma unroll
    for (int kk = 0; kk < 2; ++kk)
#pragma unroll
      for (int mi = 0; mi < 4; ++mi)
#pragma unroll
        for (int ni = 0; ni < 4; ++ni)
          acc[mi][ni] = MFMA16(af[mi][kk], bfr[ni][kk], acc[mi][ni], 0, 0, 0);
    barrier_raw();                   // WAR: reads done before next overwrite
    cur ^= 1;
  }

#pragma unroll
  for (int mi = 0; mi < 4; ++mi)
#pragma unroll
    for (int ni = 0; ni < 4; ++ni)
#pragma unroll
      for (int r = 0; r < 4; ++r) {
        const int row = m0 + wm + mi * 16 + lg * 4 + r;   // C/D: row=(lane>>4)*4+reg
        const int col = n0 + wn + ni * 16 + lr;           //      col=lane&15
        float v = acc[mi][ni][r];
        if (EPI == 0) {
          outb[(size_t)row * N + col] = f2bf(v);
        } else if (EPI == 1) {
          v += bias[col];
          v = fmaxf(v, 0.f);
          outb[(size_t)row * N + col] = f2bf(v);
        } else {
          v += bias[col] + resid[(size_t)row * N + col];
          outf[(size_t)row * N + col] = v;
        }
      }
}

// ---------------- causal flash attention: split-s partial pass -------------
// qk: bf16 [4096 tok][2048] (Q|K per head), Q pre-scaled to exp2 domain.
// vt: bf16 [1024 hd][4096 tok].
__global__ __launch_bounds__(256) void attn_partial(const u16* __restrict__ qk,
                                                    const u16* __restrict__ vt,
                                                    u16* __restrict__ Opart,
                                                    float2* __restrict__ ml) {
  const int xr = 79 - (int)blockIdx.x;  // heavy (long-range) blocks first
  int qb, ch, nc;
  if (xr < 8)       { qb = xr;                ch = 0;            nc = 1; }
  else if (xr < 24) { qb = 8 + ((xr - 8) >> 1);  ch = (xr - 8) & 1;  nc = 2; }
  else if (xr < 48) { qb = 16 + (xr - 24) / 3;   ch = (xr - 24) % 3; nc = 3; }
  else              { qb = 24 + ((xr - 48) >> 2); ch = (xr - 48) & 3; nc = 4; }
  const int nt_tot = qb + 1;
  const int t0 = (ch * nt_tot) / nc;
  const int t1 = ((ch + 1) * nt_tot) / nc;
  const int bh = blockIdx.y, b = bh >> 4, h = bh & 15;
  const int slot = bh * 80 + xr;
  const int q0 = qb * 64;
  const int tid = threadIdx.x, lane = tid & 63, w = tid >> 6;
  const int lr = lane & 15, lg = lane >> 4;
  __shared__ alignas(16) u16 sK[2][64 * 64];   // [s][d], 16B-granule XOR swizzle
  __shared__ alignas(16) u16 sV[2][64 * 64];   // [d][s], same swizzle
  __shared__ alignas(16) u16 sP[4][16 * 64];   // per-wave P, XOR-swizzled

  const size_t qrow = (size_t)(b * 2048 + q0 + w * 16 + lr) * 2048 + h * 64;
  const bf16x8 aq0 = ldbf8(qk + qrow + lg * 8);
  const bf16x8 aq1 = ldbf8(qk + qrow + 32 + lg * 8);

  float m_i[4], l_i[4];   // l_i: PER-LANE partial sums (reduced in epilogue)
  f32x4 acc[4];
#pragma unroll
  for (int r = 0; r < 4; ++r) { m_i[r] = -1e30f; l_i[r] = 0.f; }
#pragma unroll
  for (int dn = 0; dn < 4; ++dn) acc[dn] = f32x4{0.f, 0.f, 0.f, 0.f};

  auto stage = [&](int buf, int s0) {
#pragma unroll
    for (int i = 0; i < 2; ++i) {
      const int c = w * 2 + i;
      const int g = c * 64 + lane;
      const int row = g >> 3;
      const int cs = (g & 7) ^ (row & 7);
      gll16(qk + (size_t)(b * 2048 + s0 + row) * 2048 + 1024 + h * 64 + cs * 8,
            &sK[buf][c * 512]);
      gll16(vt + (size_t)(h * 64 + row) * 4096 + b * 2048 + s0 + cs * 8,
            &sV[buf][c * 512]);
    }
  };

  stage(0, t0 * 64);

  for (int t = t0; t < t1; ++t) {
    const int buf = (t - t0) & 1;
    if (t + 1 < t1) {
      stage(buf ^ 1, (t + 1) * 64);
      wait_vm<4>();
    } else {
      wait_vm<0>();
    }
    barrier_raw();

    const u16* Kb = sK[buf];
    const u16* Vb = sV[buf];
    f32x4 sf[4];
    __builtin_amdgcn_s_setprio(1);
#pragma unroll
    for (int sn = 0; sn < 4; ++sn) {  // S[16q x 64s] = Q . K^T (exp2 domain)
      const int row = sn * 16 + lr;
      const int x7 = lr & 7;
      bf16x8 k0f = ldbf8(&Kb[row * 64 + ((lg ^ x7) * 8)]);
      bf16x8 k1f = ldbf8(&Kb[row * 64 + (((4 + lg) ^ x7) * 8)]);
      f32x4 z = {0.f, 0.f, 0.f, 0.f};
      z = MFMA16(aq0, k0f, z, 0, 0, 0);
      z = MFMA16(aq1, k1f, z, 0, 0, 0);
      sf[sn] = z;
    }
    __builtin_amdgcn_s_setprio(0);

    if (t == nt_tot - 1) {  // causal mask (last tile only)
      const int qlb = w * 16 + lg * 4;
#pragma unroll
      for (int sn = 0; sn < 4; ++sn)
#pragma unroll
        for (int r = 0; r < 4; ++r)
          if (sn * 16 + lr > qlb + r) sf[sn][r] = -1e30f;
    }

    // defer-max fast path: full reduce+rescale only when growth > 8
    float pm[4];
    bool need = false;
#pragma unroll
    for (int r = 0; r < 4; ++r) {
      pm[r] = fmaxf(fmaxf(sf[0][r], sf[1][r]), fmaxf(sf[2][r], sf[3][r]));
      need = need || (pm[r] > m_i[r] + 8.f);
    }
    if (__any(need)) {
#pragma unroll
      for (int r = 0; r < 4; ++r) {
        float mx = pm[r];
        mx = fmaxf(mx, __shfl_xor(mx, 1, 16));
        mx = fmaxf(mx, __shfl_xor(mx, 2, 16));
        mx = fmaxf(mx, __shfl_xor(mx, 4, 16));
        mx = fmaxf(mx, __shfl_xor(mx, 8, 16));
        const float mnew = fmaxf(m_i[r], mx);
        const float al = exp2f(m_i[r] - mnew);
        l_i[r] *= al;
        acc[0][r] *= al; acc[1][r] *= al; acc[2][r] *= al; acc[3][r] *= al;
        m_i[r] = mnew;
      }
    }

    // P = exp2(S - m); per-lane l accumulation; swizzled P store
    const int x7p = lr & 7;
#pragma unroll
    for (int r = 0; r < 4; ++r) {
      const float p0 = exp2f(sf[0][r] - m_i[r]), p1 = exp2f(sf[1][r] - m_i[r]);
      const float p2 = exp2f(sf[2][r] - m_i[r]), p3 = exp2f(sf[3][r] - m_i[r]);
      l_i[r] += (p0 + p1) + (p2 + p3);
      const int prow = lg * 4 + r;
      const int pb = prow * 64, px = prow & 7;
      sP[w][pb + (((lr >> 3) ^ px) * 8) + (lr & 7)]       = f2bf(p0);
      sP[w][pb + (((2 + (lr >> 3)) ^ px) * 8) + (lr & 7)] = f2bf(p1);
      sP[w][pb + (((4 + (lr >> 3)) ^ px) * 8) + (lr & 7)] = f2bf(p2);
      sP[w][pb + (((6 + (lr >> 3)) ^ px) * 8) + (lr & 7)] = f2bf(p3);
    }

    // O += P . V   (wave-local P; compiler inserts lgkmcnt for the RAW)
    const bf16x8 pa0 = ldbf8(&sP[w][lr * 64 + ((lg ^ x7p) * 8)]);
    const bf16x8 pa1 = ldbf8(&sP[w][lr * 64 + (((4 + lg) ^ x7p) * 8)]);
    __builtin_amdgcn_s_setprio(1);
#pragma unroll
    for (int dn = 0; dn < 4; ++dn) {
      const int row = dn * 16 + lr;
      bf16x8 v0f = ldbf8(&Vb[row * 64 + ((lg ^ x7p) * 8)]);
      bf16x8 v1f = ldbf8(&Vb[row * 64 + (((4 + lg) ^ x7p) * 8)]);
      acc[dn] = MFMA16(pa0, v0f, acc[dn], 0, 0, 0);
      acc[dn] = MFMA16(pa1, v1f, acc[dn], 0, 0, 0);
    }
    __builtin_amdgcn_s_setprio(0);
    barrier_raw();  // WAR guard before next stage overwrites
  }

  // partial epilogue: reduce per-lane l, write unnormalized O (bf16) + (m,l)
  const int rbase = w * 16 + lg * 4;
#pragma unroll
  for (int r = 0; r < 4; ++r) {
    float ls = l_i[r];
    ls += __shfl_xor(ls, 1, 16);
    ls += __shfl_xor(ls, 2, 16);
    ls += __shfl_xor(ls, 4, 16);
    ls += __shfl_xor(ls, 8, 16);
    const int row = rbase + r;
    if (lr == 0) ml[(size_t)slot * 64 + row] = make_float2(m_i[r], ls);
#pragma unroll
    for (int dn = 0; dn < 4; ++dn)
      Opart[((size_t)slot * 64 + row) * 64 + dn * 16 + lr] = f2bf(acc[dn][r]);
  }
}

// ---------------- attention merge + residual -------------------------------
__global__ __launch_bounds__(256) void attn_merge(const u16* __restrict__ Opart,
                                                  const float2* __restrict__ ml,
                                                  const float* __restrict__ x,
                                                  float* __restrict__ x2) {
  const int qb = blockIdx.x, bh = blockIdx.y, b = bh >> 4, h = bh & 15;
  int nc, s0;
  if (qb < 8)       { nc = 1; s0 = qb; }
  else if (qb < 16) { nc = 2; s0 = 8 + (qb - 8) * 2; }
  else if (qb < 24) { nc = 3; s0 = 24 + (qb - 16) * 3; }
  else              { nc = 4; s0 = 48 + (qb - 24) * 4; }
  const size_t slot0 = (size_t)bh * 80 + s0;
  const int tid = threadIdx.x;
  const int row = tid >> 2, d0 = (tid & 3) * 16;

  float wgt[4];
  float mmax = -1e30f, lsum = 0.f;
  for (int i = 0; i < nc; ++i) {
    float2 v = ml[(slot0 + i) * 64 + row];
    wgt[i] = v.x;
    mmax = fmaxf(mmax, v.x);
  }
  for (int i = 0; i < nc; ++i) {
    float2 v = ml[(slot0 + i) * 64 + row];
    wgt[i] = exp2f(wgt[i] - mmax);
    lsum += wgt[i] * v.y;
  }
  const float inv = 1.0f / lsum;

#pragma unroll
  for (int half = 0; half < 2; ++half) {
    const int d = d0 + half * 8;
    float o[8] = {0.f, 0.f, 0.f, 0.f, 0.f, 0.f, 0.f, 0.f};
    for (int i = 0; i < nc; ++i) {
      u16x8 v = *reinterpret_cast<const u16x8*>(&Opart[((slot0 + i) * 64 + row) * 64 + d]);
#pragma unroll
      for (int j = 0; j < 8; ++j) o[j] += wgt[i] * bf2f(v[j]);
    }
    const size_t idx = ((size_t)(b * 2048 + qb * 64 + row)) * 1024 + h * 64 + d;
    float4 x0 = *reinterpret_cast<const float4*>(x + idx);
    float4 x1 = *reinterpret_cast<const float4*>(x + idx + 4);
    float4 o0 = make_float4(x0.x + o[0] * inv, x0.y + o[1] * inv, x0.z + o[2] * inv, x0.w + o[3] * inv);
    float4 o1 = make_float4(x1.x + o[4] * inv, x1.y + o[5] * inv, x1.z + o[6] * inv, x1.w + o[7] * inv);
    *reinterpret_cast<float4*>(x2 + idx) = o0;
    *reinterpret_cast<float4*>(x2 + idx + 4) = o1;
  }
}

// ---------------------------------------------------------------------------
extern "C" void kernel_launch(void* const* d_in, const int* in_sizes, int n_in,
                              void* d_out, int out_size, void* d_ws, size_t ws_size,
                              hipStream_t stream) {
  const float* x   = (const float*)d_in[0];
  const float* Wq  = (const float*)d_in[1];
  const float* Wk  = (const float*)d_in[2];
  const float* Wv  = (const float*)d_in[3];
  const float* W1  = (const float*)d_in[4];
  const float* b1  = (const float*)d_in[5];
  const float* W2  = (const float*)d_in[6];
  const float* b2  = (const float*)d_in[7];
  const float* g1  = (const float*)d_in[8];
  const float* be1 = (const float*)d_in[9];
  const float* g2  = (const float*)d_in[10];
  const float* be2 = (const float*)d_in[11];
  float* out = (float*)d_out;

  char* ws = (char*)d_ws;
  size_t off = 0;
  auto alloc = [&](size_t bytes) { char* p = ws + off; off += (bytes + 255) & ~(size_t)255; return p; };
  u16*    qkb   = (u16*)alloc(4096ull * 2048 * 2);   // [tok][Q|K]          16MB
  u16*    vtb   = (u16*)alloc(1024ull * 4096 * 2);   // [hd][tok]            8MB
  (void)alloc(4096ull * 1024 * 2);                   // h1 overflow region   8MB
  u16*    h1    = qkb;                               // MLP1 out aliases qk+vt+overflow (32MB)
  float*  x2    = (float*)alloc(4096ull * 1024 * 4); // x + attn            16MB
  u16*    hbuf  = (u16*)alloc(4096ull * 1024 * 2);   // LN outputs           8MB
  u16*    wqkvt = (u16*)alloc(3072ull * 1024 * 2);
  u16*    w1t   = (u16*)alloc(4096ull * 1024 * 2);
  u16*    w2t   = (u16*)alloc(1024ull * 4096 * 2);
  float2* part  = (float2*)alloc(2048ull * 8 * 8);
  float2* stats = (float2*)alloc(2048ull * 8);
  u16*    Opart = (u16*)alloc(32ull * 80 * 64 * 64 * 2);   // ~21MB
  float2* ml    = (float2*)alloc(32ull * 80 * 64 * 8);     // ~1.3MB
  (void)ws_size; (void)in_sizes; (void)n_in; (void)out_size;

  // weight prep (bf16, B-transposed); softmax scale folded into Wq
  const float SC = 0.03125f * 1.44269504088896341f;  // C^-0.5 * log2(e)
  transpose_head<<<dim3(16, 16), 256, 0, stream>>>(Wq, wqkvt, 0, SC);
  transpose_head<<<dim3(16, 16), 256, 0, stream>>>(Wk, wqkvt, 1024, 1.0f);
  transpose_head<<<dim3(16, 16), 256, 0, stream>>>(Wv, wqkvt, 2048, 1.0f);
  transpose_big<<<dim3(16, 64), 256, 0, stream>>>(W1, w1t, 1024, 4096);
  transpose_big<<<dim3(64, 16), 256, 0, stream>>>(W2, w2t, 4096, 1024);

  // LN1 (over T) -> hbuf
  ln_partial<<<dim3(32, 8), 256, 0, stream>>>(x, part);
  ln_stats<<<8, 256, 0, stream>>>(part, stats);
  ln_apply<<<4096, 256, 0, stream>>>(x, stats, g1, be1, hbuf);

  // QK GEMM: [4096,1024] x W_qk^T -> qkb [4096][2048]
  gemm_kernel<0><<<dim3(16, 32), 256, 0, stream>>>(hbuf, wqkvt, qkb, nullptr, nullptr, nullptr, 2048, 1024);
  // V^T GEMM: Wv^T [1024,1024] x LN1^T -> vtb [1024][4096]
  gemm_kernel<0><<<dim3(32, 8), 256, 0, stream>>>(wqkvt + 2048 * 1024, hbuf, vtb, nullptr, nullptr, nullptr, 4096, 1024);

  // attention: split-s partials, then merge + residual -> x2 (f32)
  attn_partial<<<dim3(80, 32), 256, 0, stream>>>(qkb, vtb, Opart, ml);
  attn_merge<<<dim3(32, 32), 256, 0, stream>>>(Opart, ml, x, x2);

  // LN2 (over T) -> hbuf
  ln_partial<<<dim3(32, 8), 256, 0, stream>>>(x2, part);
  ln_stats<<<8, 256, 0, stream>>>(part, stats);
  ln_apply<<<4096, 256, 0, stream>>>(x2, stats, g2, be2, hbuf);

  // MLP1: relu(h @ W1 + b1) -> h1 (bf16 [4096][4096])
  gemm_kernel<1><<<dim3(32, 32), 256, 0, stream>>>(hbuf, w1t, h1, nullptr, b1, nullptr, 4096, 1024);

  // MLP2: x2 + h1 @ W2 + b2 -> out (f32)
  gemm_kernel<2><<<dim3(8, 32), 256, 0, stream>>>(h1, w2t, nullptr, out, b2, x2, 1024, 4096);
}